// Round 3
// baseline (564.405 us; speedup 1.0000x reference)
//
#include <hip/hip_runtime.h>
#include <hip/hip_bf16.h>

// SimpleRNN: chunked gated-linear-attention scan + exact causal softmax attention + projections.
// B=4, T=2048, H=512, K=V=128, O=512. Chunk S=32, NC=64.
// Precision design: scores = ov.ov amplify ov relative error by ~5000x, so the whole
// ov pipeline runs in split-bf16 (hi+lo, ~17 bit) MFMA with fp32/f64 scalar math.

typedef __attribute__((ext_vector_type(8))) short bf16x8;
typedef __attribute__((ext_vector_type(4))) float f32x4;
typedef __attribute__((ext_vector_type(4))) short short4v;

#define MFMA(a,b,c) __builtin_amdgcn_mfma_f32_16x16x32_bf16(a,b,c,0,0,0)

__device__ __forceinline__ short f2b(float x){
  union { float f; unsigned u; } v; v.f = x;
  unsigned r = v.u + 0x7fffu + ((v.u >> 16) & 1u);   // RTNE
  return (short)(r >> 16);
}
__device__ __forceinline__ float b2f(short h){
  union { unsigned u; float f; } v;
  v.u = ((unsigned)(unsigned short)h) << 16;
  return v.f;
}
__device__ __forceinline__ void split2(float x, short& h, short& l){
  h = f2b(x);
  l = f2b(x - b2f(h));
}

// ---------------- f32 -> (hi, lo) bf16 split ----------------
__global__ void k_split(const float* __restrict__ in, short* __restrict__ hi,
                        short* __restrict__ lo, int n){
  int i = (blockIdx.x * blockDim.x + threadIdx.x) * 4;
  if (i < n){
    float4 v = *(const float4*)(in + i);
    short4v h, l;
    short th, tl;
    split2(v.x, th, tl); h.x = th; l.x = tl;
    split2(v.y, th, tl); h.y = th; l.y = tl;
    split2(v.z, th, tl); h.z = th; l.z = tl;
    split2(v.w, th, tl); h.w = th; l.w = tl;
    *(short4v*)(hi + i) = h;
    *(short4v*)(lo + i) = l;
  }
}

// ---------------- f32 -> bf16 (for out_w only) ----------------
__global__ void k_cvt(const float* __restrict__ in, short* __restrict__ out, int n){
  int i = (blockIdx.x * blockDim.x + threadIdx.x) * 4;
  if (i < n){
    float4 v = *(const float4*)(in + i);
    short4v o; o.x = f2b(v.x); o.y = f2b(v.y); o.z = f2b(v.z); o.w = f2b(v.w);
    *(short4v*)(out + i) = o;
  }
}

// ---------------- split GEMM-NT (4-pass): qkgv = X W^T + b, fused activations ----------------
// M=8192, N=512, K=512. Writes q (raw), sigmoid->kg, logsigmoid(gate)->lg, tanh->vv (fp32).
__global__ __launch_bounds__(256) void k_gemm1(
    const short* __restrict__ Ah, const short* __restrict__ Al,
    const short* __restrict__ Bh, const short* __restrict__ Bl,
    const float* __restrict__ bias,
    float* __restrict__ q_o, float* __restrict__ kg_o,
    float* __restrict__ lg_o, float* __restrict__ vv_o)
{
  const int Kd = 512;
  __shared__ __align__(16) short Ash[128][40], Asl[128][40];
  __shared__ __align__(16) short Bsh[64][40],  Bsl[64][40];
  const int m0 = blockIdx.x * 128, n0 = blockIdx.y * 64;
  const int tid = threadIdx.x, lane = tid & 63, w = tid >> 6;
  const int wr = w >> 1, wc = w & 1;
  const int coll = lane & 15, rq = lane >> 4;
  f32x4 acc[4][2];
#pragma unroll
  for (int i = 0; i < 4; i++)
#pragma unroll
    for (int j = 0; j < 2; j++) acc[i][j] = (f32x4){0.f,0.f,0.f,0.f};

  const int ar = tid >> 1, ac = (tid & 1) * 16;
  const int br = tid >> 2, bc = (tid & 3) * 8;

  for (int k0 = 0; k0 < Kd; k0 += 32){
    __syncthreads();
    { size_t g = (size_t)(m0 + ar) * Kd + k0 + ac;
      *(bf16x8*)&Ash[ar][ac]     = *(const bf16x8*)(Ah + g);
      *(bf16x8*)&Ash[ar][ac + 8] = *(const bf16x8*)(Ah + g + 8);
      *(bf16x8*)&Asl[ar][ac]     = *(const bf16x8*)(Al + g);
      *(bf16x8*)&Asl[ar][ac + 8] = *(const bf16x8*)(Al + g + 8); }
    { size_t g = (size_t)(n0 + br) * Kd + k0 + bc;
      *(bf16x8*)&Bsh[br][bc] = *(const bf16x8*)(Bh + g);
      *(bf16x8*)&Bsl[br][bc] = *(const bf16x8*)(Bl + g); }
    __syncthreads();
    bf16x8 ah[4], al[4], bh[2], bl[2];
#pragma unroll
    for (int mi = 0; mi < 4; mi++){
      ah[mi] = *(const bf16x8*)&Ash[wr*64 + mi*16 + coll][rq*8];
      al[mi] = *(const bf16x8*)&Asl[wr*64 + mi*16 + coll][rq*8];
    }
#pragma unroll
    for (int ni = 0; ni < 2; ni++){
      bh[ni] = *(const bf16x8*)&Bsh[wc*32 + ni*16 + coll][rq*8];
      bl[ni] = *(const bf16x8*)&Bsl[wc*32 + ni*16 + coll][rq*8];
    }
#pragma unroll
    for (int mi = 0; mi < 4; mi++)
#pragma unroll
      for (int ni = 0; ni < 2; ni++){
        acc[mi][ni] = MFMA(ah[mi], bh[ni], acc[mi][ni]);
        acc[mi][ni] = MFMA(ah[mi], bl[ni], acc[mi][ni]);
        acc[mi][ni] = MFMA(al[mi], bh[ni], acc[mi][ni]);
        acc[mi][ni] = MFMA(al[mi], bl[ni], acc[mi][ni]);
      }
  }
#pragma unroll
  for (int mi = 0; mi < 4; mi++)
#pragma unroll
  for (int ni = 0; ni < 2; ni++){
    int gn = n0 + wc*32 + ni*16 + coll;
    float bsv = bias[gn];
    int sec = gn >> 7, jj = gn & 127;
#pragma unroll
    for (int r = 0; r < 4; r++){
      int gm = m0 + wr*64 + mi*16 + rq*4 + r;
      float v = acc[mi][ni][r] + bsv;
      size_t idx = (size_t)gm * 128 + jj;
      if (sec == 0)      q_o[idx] = v;
      else if (sec == 1) kg_o[idx] = 1.f / (1.f + __expf(-v));
      else if (sec == 2) lg_o[idx] = (v > 0.f) ? -log1pf(__expf(-v)) : (v - log1pf(__expf(v)));
      else               vv_o[idx] = tanhf(v);
    }
  }
}

// ---------------- per-(b,chunk) prep: f64 cum-log-gates, split q~/k~/k^T/V^T ----------------
__global__ __launch_bounds__(128) void k_prep(
  const float* __restrict__ q_f, const float* __restrict__ kg_f,
  const float* __restrict__ lg_f, const float* __restrict__ vv_f,
  short* __restrict__ qth, short* __restrict__ qtl,
  short* __restrict__ kth, short* __restrict__ ktl,
  short* __restrict__ khTh, short* __restrict__ khTl,
  short* __restrict__ vvTh, short* __restrict__ vvTl,
  float* __restrict__ Dend)
{
  const int bc = blockIdx.x;                 // b*64 + ck
  const int kx = threadIdx.x;                // 0..127
  const size_t base = ((size_t)(bc >> 6) * 2048 + (size_t)(bc & 63) * 32) * 128 + kx;
  double L[32];
  double Lr = 0.0;
#pragma unroll
  for (int s = 0; s < 32; s++){
    size_t idx = base + (size_t)s * 128;
    Lr += (double)lg_f[idx];
    L[s] = Lr;
    float lam  = __expf((float)Lr);
    float ilam = __expf((float)(-Lr));
    short h, l;
    split2(q_f[idx] * lam, h, l);  qth[idx] = h; qtl[idx] = l;   // q~ = q * Lambda
    split2(kg_f[idx] * ilam, h, l); kth[idx] = h; ktl[idx] = l;  // k~ = k / Lambda
  }
  const double Lend = Lr;
  Dend[(size_t)bc * 128 + kx] = (float)exp(Lend);   // f64 exp: decay chain stays accurate
  __align__(16) short bufh[32], bufl[32];
#pragma unroll
  for (int s = 0; s < 32; s++){
    size_t idx = base + (size_t)s * 128;
    short h, l;
    split2(kg_f[idx] * __expf((float)(Lend - L[s])), h, l);   // k^ <= k
    bufh[s] = h; bufl[s] = l;
  }
  { short* dh = khTh + ((size_t)bc * 128 + kx) * 32;
    short* dl = khTl + ((size_t)bc * 128 + kx) * 32;
#pragma unroll
    for (int i = 0; i < 32; i += 8){
      *(bf16x8*)(dh + i) = *(const bf16x8*)(bufh + i);
      *(bf16x8*)(dl + i) = *(const bf16x8*)(bufl + i);
    } }
#pragma unroll
  for (int s = 0; s < 32; s++){
    short h, l;
    split2(vv_f[base + (size_t)s * 128], h, l);
    bufh[s] = h; bufl[s] = l;
  }
  { short* dh = vvTh + ((size_t)bc * 128 + kx) * 32;
    short* dl = vvTl + ((size_t)bc * 128 + kx) * 32;
#pragma unroll
    for (int i = 0; i < 32; i += 8){
      *(bf16x8*)(dh + i) = *(const bf16x8*)(bufh + i);
      *(bf16x8*)(dl + i) = *(const bf16x8*)(bufl + i);
    } }
}

// ---------------- state scan over chunks (3-pass split), grid = B ----------------
__global__ __launch_bounds__(256) void k_scan(
  const short* __restrict__ khTh, const short* __restrict__ khTl,
  const short* __restrict__ vvTh, const short* __restrict__ vvTl,
  const float* __restrict__ Dend, const float* __restrict__ cell0,
  short* __restrict__ sth, short* __restrict__ stl, float* __restrict__ Cfin)
{
  const int b = blockIdx.x;
  const int tid = threadIdx.x, lane = tid & 63, w = tid >> 6;
  const int coll = lane & 15, rq = lane >> 4;
  const int vbase = w * 32;
  f32x4 acc[2][8];
#pragma unroll
  for (int vi = 0; vi < 2; vi++)
#pragma unroll
  for (int ki = 0; ki < 8; ki++)
#pragma unroll
  for (int r = 0; r < 4; r++){
    int v = vbase + vi*16 + rq*4 + r;
    int k = ki*16 + coll;
    acc[vi][ki][r] = cell0[((size_t)b * 128 + k) * 128 + v];
  }
  for (int ck = 0; ck < 64; ck++){
    const size_t cb = (size_t)b * 64 + ck;
#pragma unroll
    for (int vi = 0; vi < 2; vi++)
#pragma unroll
    for (int ki = 0; ki < 8; ki++){
      int v = vbase + vi*16 + rq*4;
      int k = ki*16 + coll;
      short* ph = sth + (cb * 128 + v) * 128 + k;
      short* pl = stl + (cb * 128 + v) * 128 + k;
#pragma unroll
      for (int r = 0; r < 4; r++){
        short h, l; split2(acc[vi][ki][r], h, l);
        ph[(size_t)r * 128] = h; pl[(size_t)r * 128] = l;
      }
    }
    bf16x8 avh[2], avl[2], bkh[8], bkl[8];
#pragma unroll
    for (int vi = 0; vi < 2; vi++){
      size_t g = (cb * 128 + vbase + vi*16 + coll) * 32 + rq*8;
      avh[vi] = *(const bf16x8*)(vvTh + g);
      avl[vi] = *(const bf16x8*)(vvTl + g);
    }
#pragma unroll
    for (int ki = 0; ki < 8; ki++){
      size_t g = (cb * 128 + ki*16 + coll) * 32 + rq*8;
      bkh[ki] = *(const bf16x8*)(khTh + g);
      bkl[ki] = *(const bf16x8*)(khTl + g);
    }
#pragma unroll
    for (int ki = 0; ki < 8; ki++){
      float d = Dend[cb * 128 + ki*16 + coll];
#pragma unroll
      for (int vi = 0; vi < 2; vi++){
#pragma unroll
        for (int r = 0; r < 4; r++) acc[vi][ki][r] *= d;
        acc[vi][ki] = MFMA(avh[vi], bkh[ki], acc[vi][ki]);
        acc[vi][ki] = MFMA(avh[vi], bkl[ki], acc[vi][ki]);
        acc[vi][ki] = MFMA(avl[vi], bkh[ki], acc[vi][ki]);
      }
    }
  }
#pragma unroll
  for (int vi = 0; vi < 2; vi++)
#pragma unroll
  for (int ki = 0; ki < 8; ki++)
#pragma unroll
  for (int r = 0; r < 4; r++){
    int v = vbase + vi*16 + rq*4 + r;
    int k = ki*16 + coll;
    Cfin[((size_t)b * 128 + k) * 128 + v] = acc[vi][ki][r];
  }
}

// ---------------- per-(b,chunk) outputs (3-pass split): o^T = C^T q~^T + V^T A^T ----------------
__global__ __launch_bounds__(256) void k_chunkout(
  const short* __restrict__ qth, const short* __restrict__ qtl,
  const short* __restrict__ kth, const short* __restrict__ ktl,
  const short* __restrict__ vvTh, const short* __restrict__ vvTl,
  const short* __restrict__ sth, const short* __restrict__ stl,
  short* __restrict__ ovT, short* __restrict__ ovc,
  short* __restrict__ ovqh, short* __restrict__ ovql)
{
  __shared__ __align__(16) short ATh[32][40], ATl[32][40];
  const int bc = blockIdx.x;
  const int b = bc >> 6, ck = bc & 63;
  const int tid = threadIdx.x, lane = tid & 63, w = tid >> 6;
  const int coll = lane & 15, rq = lane >> 4;
  const size_t tbase = (size_t)b * 2048 + (size_t)ck * 32;
  {
    const int si = w >> 1, ti = w & 1;
    f32x4 aA = (f32x4){0.f,0.f,0.f,0.f};
#pragma unroll
    for (int kit = 0; kit < 4; kit++){
      size_t ga = (tbase + si*16 + coll) * 128 + kit*32 + rq*8;
      size_t gb = (tbase + ti*16 + coll) * 128 + kit*32 + rq*8;
      bf16x8 a3h = *(const bf16x8*)(kth + ga), a3l = *(const bf16x8*)(ktl + ga);
      bf16x8 b3h = *(const bf16x8*)(qth + gb), b3l = *(const bf16x8*)(qtl + gb);
      aA = MFMA(a3h, b3h, aA);
      aA = MFMA(a3h, b3l, aA);
      aA = MFMA(a3l, b3h, aA);
    }
#pragma unroll
    for (int r = 0; r < 4; r++){
      int s = si*16 + rq*4 + r, t = ti*16 + coll;
      float val = (s <= t) ? aA[r] : 0.f;     // causal mask, diag kept
      short h, l; split2(val, h, l);
      ATh[t][s] = h; ATl[t][s] = l;
    }
  }
  __syncthreads();
  const int vb = w * 32;
  f32x4 o[2][2];
#pragma unroll
  for (int vi = 0; vi < 2; vi++)
#pragma unroll
    for (int ti = 0; ti < 2; ti++) o[vi][ti] = (f32x4){0.f,0.f,0.f,0.f};
#pragma unroll
  for (int kit = 0; kit < 4; kit++){
    bf16x8 aCh[2], aCl[2], bqh[2], bql[2];
#pragma unroll
    for (int vi = 0; vi < 2; vi++){
      size_t g = ((size_t)bc * 128 + vb + vi*16 + coll) * 128 + kit*32 + rq*8;
      aCh[vi] = *(const bf16x8*)(sth + g);
      aCl[vi] = *(const bf16x8*)(stl + g);
    }
#pragma unroll
    for (int ti = 0; ti < 2; ti++){
      size_t g = (tbase + ti*16 + coll) * 128 + kit*32 + rq*8;
      bqh[ti] = *(const bf16x8*)(qth + g);
      bql[ti] = *(const bf16x8*)(qtl + g);
    }
#pragma unroll
    for (int vi = 0; vi < 2; vi++)
#pragma unroll
      for (int ti = 0; ti < 2; ti++){
        o[vi][ti] = MFMA(aCh[vi], bqh[ti], o[vi][ti]);
        o[vi][ti] = MFMA(aCh[vi], bql[ti], o[vi][ti]);
        o[vi][ti] = MFMA(aCl[vi], bqh[ti], o[vi][ti]);
      }
  }
  {
    bf16x8 a2h[2], a2l[2], b2h[2], b2l[2];
#pragma unroll
    for (int vi = 0; vi < 2; vi++){
      size_t g = ((size_t)bc * 128 + vb + vi*16 + coll) * 32 + rq*8;
      a2h[vi] = *(const bf16x8*)(vvTh + g);
      a2l[vi] = *(const bf16x8*)(vvTl + g);
    }
#pragma unroll
    for (int ti = 0; ti < 2; ti++){
      b2h[ti] = *(const bf16x8*)&ATh[ti*16 + coll][rq*8];
      b2l[ti] = *(const bf16x8*)&ATl[ti*16 + coll][rq*8];
    }
#pragma unroll
    for (int vi = 0; vi < 2; vi++)
#pragma unroll
      for (int ti = 0; ti < 2; ti++){
        o[vi][ti] = MFMA(a2h[vi], b2h[ti], o[vi][ti]);
        o[vi][ti] = MFMA(a2h[vi], b2l[ti], o[vi][ti]);
        o[vi][ti] = MFMA(a2l[vi], b2h[ti], o[vi][ti]);
      }
  }
#pragma unroll
  for (int vi = 0; vi < 2; vi++)
#pragma unroll
  for (int ti = 0; ti < 2; ti++)
#pragma unroll
  for (int r = 0; r < 4; r++){
    int v = vb + vi*16 + rq*4 + r;
    int tl = ti*16 + coll;
    float val = o[vi][ti][r];
    short h, l; split2(val, h, l);
    ovT[((size_t)b * 128 + v) * 2048 + (size_t)ck * 32 + tl] = h;  // [b][v][t] bf16 (PV operand)
    ovc[(tbase + tl) * 256 + v] = h;                                // [b][t][0:128] bf16
    ovqh[(tbase + tl) * 128 + v] = h;                               // split ov for scores
    ovql[(tbase + tl) * 128 + v] = l;
  }
}

// ---------------- causal softmax attention (flash, 4-pass split scores) ----------------
__global__ __launch_bounds__(256) void k_attn(
  const short* __restrict__ ovqh, const short* __restrict__ ovql,
  const short* __restrict__ ovT, short* __restrict__ ovc)
{
  __shared__ __align__(16) short P[4][16][40];
  const int blk = blockIdx.x;
  const int b = blk >> 5, qi = blk & 31;
  const int qbase = qi * 64;
  const int tid = threadIdx.x, lane = tid & 63, w = tid >> 6;
  const int coll = lane & 15, rq = lane >> 4;
  const int tw = qbase + w * 16;
  const size_t obase = (size_t)b * 2048;
  bf16x8 qfh[4], qfl[4];
#pragma unroll
  for (int kit = 0; kit < 4; kit++){
    size_t g = (obase + tw + coll) * 128 + kit*32 + rq*8;
    qfh[kit] = *(const bf16x8*)(ovqh + g);
    qfl[kit] = *(const bf16x8*)(ovql + g);
  }
  float m[4], l[4];
  f32x4 oa[8];
#pragma unroll
  for (int r = 0; r < 4; r++){ m[r] = -1e30f; l[r] = 0.f; }
#pragma unroll
  for (int df = 0; df < 8; df++) oa[df] = (f32x4){0.f,0.f,0.f,0.f};
  const int smaxv = tw + 15;
  for (int s0 = 0; s0 <= smaxv; s0 += 32){
    f32x4 sc[2];
#pragma unroll
    for (int sf = 0; sf < 2; sf++){
      f32x4 a = (f32x4){0.f,0.f,0.f,0.f};
#pragma unroll
      for (int kit = 0; kit < 4; kit++){
        size_t g = (obase + s0 + sf*16 + coll) * 128 + kit*32 + rq*8;
        bf16x8 kfh = *(const bf16x8*)(ovqh + g);
        bf16x8 kfl = *(const bf16x8*)(ovql + g);
        a = MFMA(qfh[kit], kfh, a);
        a = MFMA(qfh[kit], kfl, a);
        a = MFMA(qfl[kit], kfh, a);
        a = MFMA(qfl[kit], kfl, a);
      }
      sc[sf] = a;
    }
#pragma unroll
    for (int r = 0; r < 4; r++){
      int trow = tw + rq*4 + r;
      float s0v = (s0 + coll      <= trow) ? sc[0][r] : -1e30f;
      float s1v = (s0 + 16 + coll <= trow) ? sc[1][r] : -1e30f;
      float mx = fmaxf(s0v, s1v);
#pragma unroll
      for (int d = 1; d < 16; d <<= 1) mx = fmaxf(mx, __shfl_xor(mx, d));
      float mn = fmaxf(m[r], mx);
      float scale = __expf(m[r] - mn);
      float p0 = __expf(s0v - mn);
      float p1 = __expf(s1v - mn);
      float rs = p0 + p1;
#pragma unroll
      for (int d = 1; d < 16; d <<= 1) rs += __shfl_xor(rs, d);
      l[r] = l[r] * scale + rs;
      m[r] = mn;
#pragma unroll
      for (int df = 0; df < 8; df++) oa[df][r] *= scale;
      P[w][rq*4 + r][coll]      = f2b(p0);
      P[w][rq*4 + r][16 + coll] = f2b(p1);
    }
    bf16x8 pf = *(const bf16x8*)&P[w][coll][rq*8];
#pragma unroll
    for (int df = 0; df < 8; df++){
      bf16x8 vf = *(const bf16x8*)(ovT + ((size_t)b * 128 + df*16 + coll) * 2048 + s0 + rq*8);
      oa[df] = MFMA(pf, vf, oa[df]);
    }
  }
#pragma unroll
  for (int df = 0; df < 8; df++)
#pragma unroll
    for (int r = 0; r < 4; r++){
      int t = tw + rq*4 + r;
      ovc[(obase + t) * 256 + 128 + df*16 + coll] = f2b(oa[df][r] / l[r]);
    }
}

// ---------------- output GEMM (bf16 NT): out = concat(ov,ctx) @ OW^T + b ----------------
__global__ __launch_bounds__(256) void k_gemm0(
  const short* __restrict__ A, const short* __restrict__ Bw,
  const float* __restrict__ bias, float* __restrict__ out)
{
  const int Kd = 256, N = 512;
  __shared__ __align__(16) short As[128][40];
  __shared__ __align__(16) short Bs[64][40];
  const int m0 = blockIdx.x * 128, n0 = blockIdx.y * 64;
  const int tid = threadIdx.x, lane = tid & 63, w = tid >> 6;
  const int wr = w >> 1, wc = w & 1;
  const int coll = lane & 15, rq = lane >> 4;
  f32x4 acc[4][2];
#pragma unroll
  for (int i = 0; i < 4; i++)
#pragma unroll
    for (int j = 0; j < 2; j++) acc[i][j] = (f32x4){0.f,0.f,0.f,0.f};
  const int ar = tid >> 1, ac = (tid & 1) * 16;
  const int br = tid >> 2, bc = (tid & 3) * 8;
  for (int k0 = 0; k0 < Kd; k0 += 32){
    __syncthreads();
    { const short* g = A + (size_t)(m0 + ar) * Kd + k0 + ac;
      *(bf16x8*)&As[ar][ac]     = *(const bf16x8*)g;
      *(bf16x8*)&As[ar][ac + 8] = *(const bf16x8*)(g + 8); }
    { const short* g = Bw + (size_t)(n0 + br) * Kd + k0 + bc;
      *(bf16x8*)&Bs[br][bc] = *(const bf16x8*)g; }
    __syncthreads();
    bf16x8 a[4], b[2];
#pragma unroll
    for (int mi = 0; mi < 4; mi++) a[mi] = *(const bf16x8*)&As[wr*64 + mi*16 + coll][rq*8];
#pragma unroll
    for (int ni = 0; ni < 2; ni++) b[ni] = *(const bf16x8*)&Bs[wc*32 + ni*16 + coll][rq*8];
#pragma unroll
    for (int mi = 0; mi < 4; mi++)
#pragma unroll
      for (int ni = 0; ni < 2; ni++) acc[mi][ni] = MFMA(a[mi], b[ni], acc[mi][ni]);
  }
#pragma unroll
  for (int mi = 0; mi < 4; mi++)
#pragma unroll
  for (int ni = 0; ni < 2; ni++){
    int gn = n0 + wc*32 + ni*16 + coll;
    float bsv = bias[gn];
#pragma unroll
    for (int r = 0; r < 4; r++){
      int gm = m0 + wr*64 + mi*16 + rq*4 + r;
      out[(size_t)gm * N + gn] = acc[mi][ni][r] + bsv;
    }
  }
}

// ---------------- host launch ----------------
extern "C" void kernel_launch(void* const* d_in, const int* in_sizes, int n_in,
                              void* d_out, int out_size, void* d_ws, size_t ws_size,
                              hipStream_t stream){
  const float* hidden = (const float*)d_in[0];   // (4,2048,512)
  const float* cell0  = (const float*)d_in[1];   // (4,128,128)
  const float* projw  = (const float*)d_in[2];   // (512,512)
  const float* projb  = (const float*)d_in[3];   // (512,)
  const float* outw   = (const float*)d_in[4];   // (512,256)
  const float* outb   = (const float*)d_in[5];   // (512,)
  float* out = (float*)d_out;

  char* ws = (char*)d_ws;
  size_t off = 0;
  auto alloc = [&](size_t bytes) -> void* {
    void* p = ws + off;
    off += (bytes + 255) & ~(size_t)255;
    return p;
  };
  // Arena A: X split (phase 1) -> ov buffers (phase 2). 16.78 MB.
  short* Xh   = (short*)alloc(8192ULL * 512 * 2);
  short* Xl   = (short*)alloc(8192ULL * 512 * 2);
  short* ovqh = Xh;                       // 8192*128 shorts
  short* ovql = Xh + 1048576;
  short* ovT  = Xh + 2097152;             // 4*128*2048 shorts
  short* ovc  = Xh + 3145728;             // 8192*256 shorts
  // Arena B: q/kg/lg/vv f32 (phase 1) -> states hi/lo (phase 2). 16.78 MB.
  float* q_f  = (float*)alloc(8192ULL * 128 * 4);
  float* kg_f = (float*)alloc(8192ULL * 128 * 4);
  float* lg_f = (float*)alloc(8192ULL * 128 * 4);
  float* vv_f = (float*)alloc(8192ULL * 128 * 4);
  short* sth  = (short*)q_f;              // 256*128*128 shorts
  short* stl  = sth + 4194304;
  // Persistent
  short* Wh   = (short*)alloc(512ULL * 512 * 2);
  short* Wl   = (short*)alloc(512ULL * 512 * 2);
  short* OWbf = (short*)alloc(512ULL * 256 * 2);
  short* qth  = (short*)alloc(8192ULL * 128 * 2);
  short* qtl  = (short*)alloc(8192ULL * 128 * 2);
  short* kth  = (short*)alloc(8192ULL * 128 * 2);
  short* ktl  = (short*)alloc(8192ULL * 128 * 2);
  short* khTh = (short*)alloc(256ULL * 128 * 32 * 2);
  short* khTl = (short*)alloc(256ULL * 128 * 32 * 2);
  short* vvTh = (short*)alloc(256ULL * 128 * 32 * 2);
  short* vvTl = (short*)alloc(256ULL * 128 * 32 * 2);
  float* Dend = (float*)alloc(256ULL * 128 * 4);

  k_split<<<4096, 256, 0, stream>>>(hidden, Xh, Xl, 8192 * 512);
  k_split<<<256,  256, 0, stream>>>(projw,  Wh, Wl, 512 * 512);
  k_cvt<<<128, 256, 0, stream>>>(outw, OWbf, 512 * 256);

  k_gemm1<<<dim3(64, 8), 256, 0, stream>>>(Xh, Xl, Wh, Wl, projb, q_f, kg_f, lg_f, vv_f);
  k_prep<<<256, 128, 0, stream>>>(q_f, kg_f, lg_f, vv_f,
                                  qth, qtl, kth, ktl, khTh, khTl, vvTh, vvTl, Dend);
  k_scan<<<4, 256, 0, stream>>>(khTh, khTl, vvTh, vvTl, Dend, cell0,
                                sth, stl, out + 8192ULL * 512);
  k_chunkout<<<256, 256, 0, stream>>>(qth, qtl, kth, ktl, vvTh, vvTl, sth, stl,
                                      ovT, ovc, ovqh, ovql);
  k_attn<<<128, 256, 0, stream>>>(ovqh, ovql, ovT, ovc);
  k_gemm0<<<dim3(64, 8), 256, 0, stream>>>(ovc, OWbf, outb, out);
}

// Round 4
// 364.524 us; speedup vs baseline: 1.5483x; 1.5483x over previous
//
#include <hip/hip_runtime.h>
#include <hip/hip_bf16.h>

// SimpleRNN: chunked gated-linear-attention scan + exact causal softmax attention + projections.
// B=4, T=2048, H=512, K=V=128, O=512. Chunk S=32, NC=64.
// Precision design: scores = ov.ov amplify ov relative error by ~5000x, so the whole
// ov pipeline runs in split-bf16 (hi+lo, ~17 bit) MFMA with fp32/f64 scalar math.
// R3: k_scan parallelized 4 blocks -> 256 single-wave blocks (one 16x16 state tile each).

typedef __attribute__((ext_vector_type(8))) short bf16x8;
typedef __attribute__((ext_vector_type(4))) float f32x4;
typedef __attribute__((ext_vector_type(4))) short short4v;

#define MFMA(a,b,c) __builtin_amdgcn_mfma_f32_16x16x32_bf16(a,b,c,0,0,0)

__device__ __forceinline__ short f2b(float x){
  union { float f; unsigned u; } v; v.f = x;
  unsigned r = v.u + 0x7fffu + ((v.u >> 16) & 1u);   // RTNE
  return (short)(r >> 16);
}
__device__ __forceinline__ float b2f(short h){
  union { unsigned u; float f; } v;
  v.u = ((unsigned)(unsigned short)h) << 16;
  return v.f;
}
__device__ __forceinline__ void split2(float x, short& h, short& l){
  h = f2b(x);
  l = f2b(x - b2f(h));
}

// ---------------- f32 -> (hi, lo) bf16 split ----------------
__global__ void k_split(const float* __restrict__ in, short* __restrict__ hi,
                        short* __restrict__ lo, int n){
  int i = (blockIdx.x * blockDim.x + threadIdx.x) * 4;
  if (i < n){
    float4 v = *(const float4*)(in + i);
    short4v h, l;
    short th, tl;
    split2(v.x, th, tl); h.x = th; l.x = tl;
    split2(v.y, th, tl); h.y = th; l.y = tl;
    split2(v.z, th, tl); h.z = th; l.z = tl;
    split2(v.w, th, tl); h.w = th; l.w = tl;
    *(short4v*)(hi + i) = h;
    *(short4v*)(lo + i) = l;
  }
}

// ---------------- f32 -> bf16 (for out_w only) ----------------
__global__ void k_cvt(const float* __restrict__ in, short* __restrict__ out, int n){
  int i = (blockIdx.x * blockDim.x + threadIdx.x) * 4;
  if (i < n){
    float4 v = *(const float4*)(in + i);
    short4v o; o.x = f2b(v.x); o.y = f2b(v.y); o.z = f2b(v.z); o.w = f2b(v.w);
    *(short4v*)(out + i) = o;
  }
}

// ---------------- split GEMM-NT (3-pass): qkgv = X W^T + b, fused activations ----------------
// M=8192, N=512, K=512. Writes q (raw), sigmoid->kg, logsigmoid(gate)->lg, tanh->vv (fp32).
__global__ __launch_bounds__(256) void k_gemm1(
    const short* __restrict__ Ah, const short* __restrict__ Al,
    const short* __restrict__ Bh, const short* __restrict__ Bl,
    const float* __restrict__ bias,
    float* __restrict__ q_o, float* __restrict__ kg_o,
    float* __restrict__ lg_o, float* __restrict__ vv_o)
{
  const int Kd = 512;
  __shared__ __align__(16) short Ash[128][40], Asl[128][40];
  __shared__ __align__(16) short Bsh[64][40],  Bsl[64][40];
  const int m0 = blockIdx.x * 128, n0 = blockIdx.y * 64;
  const int tid = threadIdx.x, lane = tid & 63, w = tid >> 6;
  const int wr = w >> 1, wc = w & 1;
  const int coll = lane & 15, rq = lane >> 4;
  f32x4 acc[4][2];
#pragma unroll
  for (int i = 0; i < 4; i++)
#pragma unroll
    for (int j = 0; j < 2; j++) acc[i][j] = (f32x4){0.f,0.f,0.f,0.f};

  const int ar = tid >> 1, ac = (tid & 1) * 16;
  const int br = tid >> 2, bc = (tid & 3) * 8;

  for (int k0 = 0; k0 < Kd; k0 += 32){
    __syncthreads();
    { size_t g = (size_t)(m0 + ar) * Kd + k0 + ac;
      *(bf16x8*)&Ash[ar][ac]     = *(const bf16x8*)(Ah + g);
      *(bf16x8*)&Ash[ar][ac + 8] = *(const bf16x8*)(Ah + g + 8);
      *(bf16x8*)&Asl[ar][ac]     = *(const bf16x8*)(Al + g);
      *(bf16x8*)&Asl[ar][ac + 8] = *(const bf16x8*)(Al + g + 8); }
    { size_t g = (size_t)(n0 + br) * Kd + k0 + bc;
      *(bf16x8*)&Bsh[br][bc] = *(const bf16x8*)(Bh + g);
      *(bf16x8*)&Bsl[br][bc] = *(const bf16x8*)(Bl + g); }
    __syncthreads();
    bf16x8 ah[4], al[4], bh[2], bl[2];
#pragma unroll
    for (int mi = 0; mi < 4; mi++){
      ah[mi] = *(const bf16x8*)&Ash[wr*64 + mi*16 + coll][rq*8];
      al[mi] = *(const bf16x8*)&Asl[wr*64 + mi*16 + coll][rq*8];
    }
#pragma unroll
    for (int ni = 0; ni < 2; ni++){
      bh[ni] = *(const bf16x8*)&Bsh[wc*32 + ni*16 + coll][rq*8];
      bl[ni] = *(const bf16x8*)&Bsl[wc*32 + ni*16 + coll][rq*8];
    }
#pragma unroll
    for (int mi = 0; mi < 4; mi++)
#pragma unroll
      for (int ni = 0; ni < 2; ni++){
        acc[mi][ni] = MFMA(ah[mi], bh[ni], acc[mi][ni]);
        acc[mi][ni] = MFMA(ah[mi], bl[ni], acc[mi][ni]);
        acc[mi][ni] = MFMA(al[mi], bh[ni], acc[mi][ni]);
      }
  }
#pragma unroll
  for (int mi = 0; mi < 4; mi++)
#pragma unroll
  for (int ni = 0; ni < 2; ni++){
    int gn = n0 + wc*32 + ni*16 + coll;
    float bsv = bias[gn];
    int sec = gn >> 7, jj = gn & 127;
#pragma unroll
    for (int r = 0; r < 4; r++){
      int gm = m0 + wr*64 + mi*16 + rq*4 + r;
      float v = acc[mi][ni][r] + bsv;
      size_t idx = (size_t)gm * 128 + jj;
      if (sec == 0)      q_o[idx] = v;
      else if (sec == 1) kg_o[idx] = 1.f / (1.f + __expf(-v));
      else if (sec == 2) lg_o[idx] = (v > 0.f) ? -log1pf(__expf(-v)) : (v - log1pf(__expf(v)));
      else               vv_o[idx] = tanhf(v);
    }
  }
}

// ---------------- per-(b,chunk) prep: f64 cum-log-gates, split q~/k~/k^T/V^T ----------------
__global__ __launch_bounds__(128) void k_prep(
  const float* __restrict__ q_f, const float* __restrict__ kg_f,
  const float* __restrict__ lg_f, const float* __restrict__ vv_f,
  short* __restrict__ qth, short* __restrict__ qtl,
  short* __restrict__ kth, short* __restrict__ ktl,
  short* __restrict__ khTh, short* __restrict__ khTl,
  short* __restrict__ vvTh, short* __restrict__ vvTl,
  float* __restrict__ Dend)
{
  const int bc = blockIdx.x;                 // b*64 + ck
  const int kx = threadIdx.x;                // 0..127
  const size_t base = ((size_t)(bc >> 6) * 2048 + (size_t)(bc & 63) * 32) * 128 + kx;
  double L[32];
  double Lr = 0.0;
#pragma unroll
  for (int s = 0; s < 32; s++){
    size_t idx = base + (size_t)s * 128;
    Lr += (double)lg_f[idx];
    L[s] = Lr;
    float lam  = __expf((float)Lr);
    float ilam = __expf((float)(-Lr));
    short h, l;
    split2(q_f[idx] * lam, h, l);  qth[idx] = h; qtl[idx] = l;   // q~ = q * Lambda
    split2(kg_f[idx] * ilam, h, l); kth[idx] = h; ktl[idx] = l;  // k~ = k / Lambda
  }
  const double Lend = Lr;
  Dend[(size_t)bc * 128 + kx] = (float)exp(Lend);   // f64 exp: decay chain stays accurate
  __align__(16) short bufh[32], bufl[32];
#pragma unroll
  for (int s = 0; s < 32; s++){
    size_t idx = base + (size_t)s * 128;
    short h, l;
    split2(kg_f[idx] * __expf((float)(Lend - L[s])), h, l);   // k^ <= k
    bufh[s] = h; bufl[s] = l;
  }
  { short* dh = khTh + ((size_t)bc * 128 + kx) * 32;
    short* dl = khTl + ((size_t)bc * 128 + kx) * 32;
#pragma unroll
    for (int i = 0; i < 32; i += 8){
      *(bf16x8*)(dh + i) = *(const bf16x8*)(bufh + i);
      *(bf16x8*)(dl + i) = *(const bf16x8*)(bufl + i);
    } }
#pragma unroll
  for (int s = 0; s < 32; s++){
    short h, l;
    split2(vv_f[base + (size_t)s * 128], h, l);
    bufh[s] = h; bufl[s] = l;
  }
  { short* dh = vvTh + ((size_t)bc * 128 + kx) * 32;
    short* dl = vvTl + ((size_t)bc * 128 + kx) * 32;
#pragma unroll
    for (int i = 0; i < 32; i += 8){
      *(bf16x8*)(dh + i) = *(const bf16x8*)(bufh + i);
      *(bf16x8*)(dl + i) = *(const bf16x8*)(bufl + i);
    } }
}

// ---------------- state scan over chunks, grid = B*64 single-wave blocks ----------------
// Each block owns one 16x16 (k,v) tile of the state; sequential over 64 chunks with
// one-chunk-ahead register prefetch. 3-pass split MFMA per chunk.
__global__ __launch_bounds__(64) void k_scan(
  const short* __restrict__ khTh, const short* __restrict__ khTl,
  const short* __restrict__ vvTh, const short* __restrict__ vvTl,
  const float* __restrict__ Dend, const float* __restrict__ cell0,
  short* __restrict__ sth, short* __restrict__ stl, float* __restrict__ Cfin)
{
  const int blk = blockIdx.x;
  const int b = blk >> 6, tile = blk & 63;
  const int kt = tile >> 3, vt = tile & 7;
  const int lane = threadIdx.x & 63;
  const int coll = lane & 15, rq = lane >> 4;
  const int kcol = kt*16 + coll;         // k index (acc col, B-operand row, d)
  const int vrow0 = vt*16 + rq*4;        // v row base (acc rows)
  const size_t cb0 = (size_t)b * 64;

  f32x4 acc;
#pragma unroll
  for (int r = 0; r < 4; r++)
    acc[r] = cell0[((size_t)b*128 + kcol)*128 + vrow0 + r];

  // prefetch chunk 0
  size_t gv = (cb0*128 + vt*16 + coll)*32 + rq*8;
  size_t gk = (cb0*128 + kt*16 + coll)*32 + rq*8;
  bf16x8 avh = *(const bf16x8*)(vvTh + gv);
  bf16x8 avl = *(const bf16x8*)(vvTl + gv);
  bf16x8 bkh = *(const bf16x8*)(khTh + gk);
  bf16x8 bkl = *(const bf16x8*)(khTl + gk);
  float d = Dend[cb0*128 + kcol];

  for (int ck = 0; ck < 64; ck++){
    const size_t cb = cb0 + ck;
    // prefetch next chunk (branchless: last iter re-loads current, unused)
    const size_t cbn = cb0 + (ck < 63 ? ck + 1 : ck);
    size_t ngv = (cbn*128 + vt*16 + coll)*32 + rq*8;
    size_t ngk = (cbn*128 + kt*16 + coll)*32 + rq*8;
    bf16x8 navh = *(const bf16x8*)(vvTh + ngv);
    bf16x8 navl = *(const bf16x8*)(vvTl + ngv);
    bf16x8 nbkh = *(const bf16x8*)(khTh + ngk);
    bf16x8 nbkl = *(const bf16x8*)(khTl + ngk);
    float nd = Dend[cbn*128 + kcol];
    // write entering state (split bf16, layout [b,ck][v][k])
    {
      size_t sb = (cb*128 + vrow0)*128 + kcol;
#pragma unroll
      for (int r = 0; r < 4; r++){
        short h, l; split2(acc[r], h, l);
        sth[sb + (size_t)r*128] = h;
        stl[sb + (size_t)r*128] = l;
      }
    }
#pragma unroll
    for (int r = 0; r < 4; r++) acc[r] *= d;
    acc = MFMA(avh, bkh, acc);
    acc = MFMA(avh, bkl, acc);
    acc = MFMA(avl, bkh, acc);
    avh = navh; avl = navl; bkh = nbkh; bkl = nbkl; d = nd;
  }
  // final cell state -> d_out (layout [b][k][v] f32, v contiguous)
  *(f32x4*)(Cfin + ((size_t)b*128 + kcol)*128 + vrow0) = acc;
}

// ---------------- per-(b,chunk) outputs (3-pass split): o^T = C^T q~^T + V^T A^T ----------------
__global__ __launch_bounds__(256) void k_chunkout(
  const short* __restrict__ qth, const short* __restrict__ qtl,
  const short* __restrict__ kth, const short* __restrict__ ktl,
  const short* __restrict__ vvTh, const short* __restrict__ vvTl,
  const short* __restrict__ sth, const short* __restrict__ stl,
  short* __restrict__ ovT, short* __restrict__ ovc,
  short* __restrict__ ovqh, short* __restrict__ ovql)
{
  __shared__ __align__(16) short ATh[32][40], ATl[32][40];
  const int bc = blockIdx.x;
  const int b = bc >> 6, ck = bc & 63;
  const int tid = threadIdx.x, lane = tid & 63, w = tid >> 6;
  const int coll = lane & 15, rq = lane >> 4;
  const size_t tbase = (size_t)b * 2048 + (size_t)ck * 32;
  {
    const int si = w >> 1, ti = w & 1;
    f32x4 aA = (f32x4){0.f,0.f,0.f,0.f};
#pragma unroll
    for (int kit = 0; kit < 4; kit++){
      size_t ga = (tbase + si*16 + coll) * 128 + kit*32 + rq*8;
      size_t gb = (tbase + ti*16 + coll) * 128 + kit*32 + rq*8;
      bf16x8 a3h = *(const bf16x8*)(kth + ga), a3l = *(const bf16x8*)(ktl + ga);
      bf16x8 b3h = *(const bf16x8*)(qth + gb), b3l = *(const bf16x8*)(qtl + gb);
      aA = MFMA(a3h, b3h, aA);
      aA = MFMA(a3h, b3l, aA);
      aA = MFMA(a3l, b3h, aA);
    }
#pragma unroll
    for (int r = 0; r < 4; r++){
      int s = si*16 + rq*4 + r, t = ti*16 + coll;
      float val = (s <= t) ? aA[r] : 0.f;     // causal mask, diag kept
      short h, l; split2(val, h, l);
      ATh[t][s] = h; ATl[t][s] = l;
    }
  }
  __syncthreads();
  const int vb = w * 32;
  f32x4 o[2][2];
#pragma unroll
  for (int vi = 0; vi < 2; vi++)
#pragma unroll
    for (int ti = 0; ti < 2; ti++) o[vi][ti] = (f32x4){0.f,0.f,0.f,0.f};
#pragma unroll
  for (int kit = 0; kit < 4; kit++){
    bf16x8 aCh[2], aCl[2], bqh[2], bql[2];
#pragma unroll
    for (int vi = 0; vi < 2; vi++){
      size_t g = ((size_t)bc * 128 + vb + vi*16 + coll) * 128 + kit*32 + rq*8;
      aCh[vi] = *(const bf16x8*)(sth + g);
      aCl[vi] = *(const bf16x8*)(stl + g);
    }
#pragma unroll
    for (int ti = 0; ti < 2; ti++){
      size_t g = (tbase + ti*16 + coll) * 128 + kit*32 + rq*8;
      bqh[ti] = *(const bf16x8*)(qth + g);
      bql[ti] = *(const bf16x8*)(qtl + g);
    }
#pragma unroll
    for (int vi = 0; vi < 2; vi++)
#pragma unroll
      for (int ti = 0; ti < 2; ti++){
        o[vi][ti] = MFMA(aCh[vi], bqh[ti], o[vi][ti]);
        o[vi][ti] = MFMA(aCh[vi], bql[ti], o[vi][ti]);
        o[vi][ti] = MFMA(aCl[vi], bqh[ti], o[vi][ti]);
      }
  }
  {
    bf16x8 a2h[2], a2l[2], b2h[2], b2l[2];
#pragma unroll
    for (int vi = 0; vi < 2; vi++){
      size_t g = ((size_t)bc * 128 + vb + vi*16 + coll) * 32 + rq*8;
      a2h[vi] = *(const bf16x8*)(vvTh + g);
      a2l[vi] = *(const bf16x8*)(vvTl + g);
    }
#pragma unroll
    for (int ti = 0; ti < 2; ti++){
      b2h[ti] = *(const bf16x8*)&ATh[ti*16 + coll][rq*8];
      b2l[ti] = *(const bf16x8*)&ATl[ti*16 + coll][rq*8];
    }
#pragma unroll
    for (int vi = 0; vi < 2; vi++)
#pragma unroll
      for (int ti = 0; ti < 2; ti++){
        o[vi][ti] = MFMA(a2h[vi], b2h[ti], o[vi][ti]);
        o[vi][ti] = MFMA(a2h[vi], b2l[ti], o[vi][ti]);
        o[vi][ti] = MFMA(a2l[vi], b2h[ti], o[vi][ti]);
      }
  }
#pragma unroll
  for (int vi = 0; vi < 2; vi++)
#pragma unroll
  for (int ti = 0; ti < 2; ti++)
#pragma unroll
  for (int r = 0; r < 4; r++){
    int v = vb + vi*16 + rq*4 + r;
    int tl = ti*16 + coll;
    float val = o[vi][ti][r];
    short h, l; split2(val, h, l);
    ovT[((size_t)b * 128 + v) * 2048 + (size_t)ck * 32 + tl] = h;  // [b][v][t] bf16 (PV operand)
    ovc[(tbase + tl) * 256 + v] = h;                                // [b][t][0:128] bf16
    ovqh[(tbase + tl) * 128 + v] = h;                               // split ov for scores
    ovql[(tbase + tl) * 128 + v] = l;
  }
}

// ---------------- causal softmax attention (flash, 4-pass split scores) ----------------
__global__ __launch_bounds__(256) void k_attn(
  const short* __restrict__ ovqh, const short* __restrict__ ovql,
  const short* __restrict__ ovT, short* __restrict__ ovc)
{
  __shared__ __align__(16) short P[4][16][40];
  const int blk = blockIdx.x;
  const int b = blk >> 5, qi = blk & 31;
  const int qbase = qi * 64;
  const int tid = threadIdx.x, lane = tid & 63, w = tid >> 6;
  const int coll = lane & 15, rq = lane >> 4;
  const int tw = qbase + w * 16;
  const size_t obase = (size_t)b * 2048;
  bf16x8 qfh[4], qfl[4];
#pragma unroll
  for (int kit = 0; kit < 4; kit++){
    size_t g = (obase + tw + coll) * 128 + kit*32 + rq*8;
    qfh[kit] = *(const bf16x8*)(ovqh + g);
    qfl[kit] = *(const bf16x8*)(ovql + g);
  }
  float m[4], l[4];
  f32x4 oa[8];
#pragma unroll
  for (int r = 0; r < 4; r++){ m[r] = -1e30f; l[r] = 0.f; }
#pragma unroll
  for (int df = 0; df < 8; df++) oa[df] = (f32x4){0.f,0.f,0.f,0.f};
  const int smaxv = tw + 15;
  for (int s0 = 0; s0 <= smaxv; s0 += 32){
    f32x4 sc[2];
#pragma unroll
    for (int sf = 0; sf < 2; sf++){
      f32x4 a = (f32x4){0.f,0.f,0.f,0.f};
#pragma unroll
      for (int kit = 0; kit < 4; kit++){
        size_t g = (obase + s0 + sf*16 + coll) * 128 + kit*32 + rq*8;
        bf16x8 kfh = *(const bf16x8*)(ovqh + g);
        bf16x8 kfl = *(const bf16x8*)(ovql + g);
        a = MFMA(qfh[kit], kfh, a);
        a = MFMA(qfh[kit], kfl, a);
        a = MFMA(qfl[kit], kfh, a);
        a = MFMA(qfl[kit], kfl, a);
      }
      sc[sf] = a;
    }
#pragma unroll
    for (int r = 0; r < 4; r++){
      int trow = tw + rq*4 + r;
      float s0v = (s0 + coll      <= trow) ? sc[0][r] : -1e30f;
      float s1v = (s0 + 16 + coll <= trow) ? sc[1][r] : -1e30f;
      float mx = fmaxf(s0v, s1v);
#pragma unroll
      for (int d = 1; d < 16; d <<= 1) mx = fmaxf(mx, __shfl_xor(mx, d));
      float mn = fmaxf(m[r], mx);
      float scale = __expf(m[r] - mn);
      float p0 = __expf(s0v - mn);
      float p1 = __expf(s1v - mn);
      float rs = p0 + p1;
#pragma unroll
      for (int d = 1; d < 16; d <<= 1) rs += __shfl_xor(rs, d);
      l[r] = l[r] * scale + rs;
      m[r] = mn;
#pragma unroll
      for (int df = 0; df < 8; df++) oa[df][r] *= scale;
      P[w][rq*4 + r][coll]      = f2b(p0);
      P[w][rq*4 + r][16 + coll] = f2b(p1);
    }
    bf16x8 pf = *(const bf16x8*)&P[w][coll][rq*8];
#pragma unroll
    for (int df = 0; df < 8; df++){
      bf16x8 vf = *(const bf16x8*)(ovT + ((size_t)b * 128 + df*16 + coll) * 2048 + s0 + rq*8);
      oa[df] = MFMA(pf, vf, oa[df]);
    }
  }
#pragma unroll
  for (int df = 0; df < 8; df++)
#pragma unroll
    for (int r = 0; r < 4; r++){
      int t = tw + rq*4 + r;
      ovc[(obase + t) * 256 + 128 + df*16 + coll] = f2b(oa[df][r] / l[r]);
    }
}

// ---------------- output GEMM (bf16 NT): out = concat(ov,ctx) @ OW^T + b ----------------
__global__ __launch_bounds__(256) void k_gemm0(
  const short* __restrict__ A, const short* __restrict__ Bw,
  const float* __restrict__ bias, float* __restrict__ out)
{
  const int Kd = 256, N = 512;
  __shared__ __align__(16) short As[128][40];
  __shared__ __align__(16) short Bs[64][40];
  const int m0 = blockIdx.x * 128, n0 = blockIdx.y * 64;
  const int tid = threadIdx.x, lane = tid & 63, w = tid >> 6;
  const int wr = w >> 1, wc = w & 1;
  const int coll = lane & 15, rq = lane >> 4;
  f32x4 acc[4][2];
#pragma unroll
  for (int i = 0; i < 4; i++)
#pragma unroll
    for (int j = 0; j < 2; j++) acc[i][j] = (f32x4){0.f,0.f,0.f,0.f};
  const int ar = tid >> 1, ac = (tid & 1) * 16;
  const int br = tid >> 2, bc = (tid & 3) * 8;
  for (int k0 = 0; k0 < Kd; k0 += 32){
    __syncthreads();
    { const short* g = A + (size_t)(m0 + ar) * Kd + k0 + ac;
      *(bf16x8*)&As[ar][ac]     = *(const bf16x8*)g;
      *(bf16x8*)&As[ar][ac + 8] = *(const bf16x8*)(g + 8); }
    { const short* g = Bw + (size_t)(n0 + br) * Kd + k0 + bc;
      *(bf16x8*)&Bs[br][bc] = *(const bf16x8*)g; }
    __syncthreads();
    bf16x8 a[4], b[2];
#pragma unroll
    for (int mi = 0; mi < 4; mi++) a[mi] = *(const bf16x8*)&As[wr*64 + mi*16 + coll][rq*8];
#pragma unroll
    for (int ni = 0; ni < 2; ni++) b[ni] = *(const bf16x8*)&Bs[wc*32 + ni*16 + coll][rq*8];
#pragma unroll
    for (int mi = 0; mi < 4; mi++)
#pragma unroll
      for (int ni = 0; ni < 2; ni++) acc[mi][ni] = MFMA(a[mi], b[ni], acc[mi][ni]);
  }
#pragma unroll
  for (int mi = 0; mi < 4; mi++)
#pragma unroll
  for (int ni = 0; ni < 2; ni++){
    int gn = n0 + wc*32 + ni*16 + coll;
    float bsv = bias[gn];
#pragma unroll
    for (int r = 0; r < 4; r++){
      int gm = m0 + wr*64 + mi*16 + rq*4 + r;
      out[(size_t)gm * N + gn] = acc[mi][ni][r] + bsv;
    }
  }
}

// ---------------- host launch ----------------
extern "C" void kernel_launch(void* const* d_in, const int* in_sizes, int n_in,
                              void* d_out, int out_size, void* d_ws, size_t ws_size,
                              hipStream_t stream){
  const float* hidden = (const float*)d_in[0];   // (4,2048,512)
  const float* cell0  = (const float*)d_in[1];   // (4,128,128)
  const float* projw  = (const float*)d_in[2];   // (512,512)
  const float* projb  = (const float*)d_in[3];   // (512,)
  const float* outw   = (const float*)d_in[4];   // (512,256)
  const float* outb   = (const float*)d_in[5];   // (512,)
  float* out = (float*)d_out;

  char* ws = (char*)d_ws;
  size_t off = 0;
  auto alloc = [&](size_t bytes) -> void* {
    void* p = ws + off;
    off += (bytes + 255) & ~(size_t)255;
    return p;
  };
  // Arena A: X split (phase 1) -> ov buffers (phase 2). 16.78 MB.
  short* Xh   = (short*)alloc(8192ULL * 512 * 2);
  short* Xl   = (short*)alloc(8192ULL * 512 * 2);
  short* ovqh = Xh;                       // 8192*128 shorts
  short* ovql = Xh + 1048576;
  short* ovT  = Xh + 2097152;             // 4*128*2048 shorts
  short* ovc  = Xh + 3145728;             // 8192*256 shorts
  // Arena B: q/kg/lg/vv f32 (phase 1) -> states hi/lo (phase 2). 16.78 MB.
  float* q_f  = (float*)alloc(8192ULL * 128 * 4);
  float* kg_f = (float*)alloc(8192ULL * 128 * 4);
  float* lg_f = (float*)alloc(8192ULL * 128 * 4);
  float* vv_f = (float*)alloc(8192ULL * 128 * 4);
  short* sth  = (short*)q_f;              // 256*128*128 shorts
  short* stl  = sth + 4194304;
  // Persistent
  short* Wh   = (short*)alloc(512ULL * 512 * 2);
  short* Wl   = (short*)alloc(512ULL * 512 * 2);
  short* OWbf = (short*)alloc(512ULL * 256 * 2);
  short* qth  = (short*)alloc(8192ULL * 128 * 2);
  short* qtl  = (short*)alloc(8192ULL * 128 * 2);
  short* kth  = (short*)alloc(8192ULL * 128 * 2);
  short* ktl  = (short*)alloc(8192ULL * 128 * 2);
  short* khTh = (short*)alloc(256ULL * 128 * 32 * 2);
  short* khTl = (short*)alloc(256ULL * 128 * 32 * 2);
  short* vvTh = (short*)alloc(256ULL * 128 * 32 * 2);
  short* vvTl = (short*)alloc(256ULL * 128 * 32 * 2);
  float* Dend = (float*)alloc(256ULL * 128 * 4);

  k_split<<<4096, 256, 0, stream>>>(hidden, Xh, Xl, 8192 * 512);
  k_split<<<256,  256, 0, stream>>>(projw,  Wh, Wl, 512 * 512);
  k_cvt<<<128, 256, 0, stream>>>(outw, OWbf, 512 * 256);

  k_gemm1<<<dim3(64, 8), 256, 0, stream>>>(Xh, Xl, Wh, Wl, projb, q_f, kg_f, lg_f, vv_f);
  k_prep<<<256, 128, 0, stream>>>(q_f, kg_f, lg_f, vv_f,
                                  qth, qtl, kth, ktl, khTh, khTl, vvTh, vvTl, Dend);
  k_scan<<<256, 64, 0, stream>>>(khTh, khTl, vvTh, vvTl, Dend, cell0,
                                 sth, stl, out + 8192ULL * 512);
  k_chunkout<<<256, 256, 0, stream>>>(qth, qtl, kth, ktl, vvTh, vvTl, sth, stl,
                                      ovT, ovc, ovqh, ovql);
  k_attn<<<128, 256, 0, stream>>>(ovqh, ovql, ovT, ovc);
  k_gemm0<<<dim3(64, 8), 256, 0, stream>>>(ovc, OWbf, outb, out);
}

// Round 5
// 293.778 us; speedup vs baseline: 1.9212x; 1.2408x over previous
//
#include <hip/hip_runtime.h>
#include <hip/hip_bf16.h>

// SimpleRNN: chunked gated-linear-attention scan + exact causal softmax attention + projections.
// B=4, T=2048, H=512, K=V=128, O=512. Chunk S=32, NC=64.
// Precision design: scores = ov.ov amplify ov relative error by ~5000x, so the whole
// ov pipeline runs in split-bf16 (hi+lo, ~17 bit) MFMA with fp32/f64 scalar math.
// R3: k_scan parallelized 4 blocks -> 256 single-wave blocks.
// R5: k_attn flash-decoding split-S (P=8 partitions, LSE combine), 3-chain 3-pass scores.

typedef __attribute__((ext_vector_type(8))) short bf16x8;
typedef __attribute__((ext_vector_type(4))) float f32x4;
typedef __attribute__((ext_vector_type(4))) short short4v;

#define MFMA(a,b,c) __builtin_amdgcn_mfma_f32_16x16x32_bf16(a,b,c,0,0,0)

__device__ __forceinline__ short f2b(float x){
  union { float f; unsigned u; } v; v.f = x;
  unsigned r = v.u + 0x7fffu + ((v.u >> 16) & 1u);   // RTNE
  return (short)(r >> 16);
}
__device__ __forceinline__ float b2f(short h){
  union { unsigned u; float f; } v;
  v.u = ((unsigned)(unsigned short)h) << 16;
  return v.f;
}
__device__ __forceinline__ void split2(float x, short& h, short& l){
  h = f2b(x);
  l = f2b(x - b2f(h));
}

// ---------------- f32 -> (hi, lo) bf16 split ----------------
__global__ void k_split(const float* __restrict__ in, short* __restrict__ hi,
                        short* __restrict__ lo, int n){
  int i = (blockIdx.x * blockDim.x + threadIdx.x) * 4;
  if (i < n){
    float4 v = *(const float4*)(in + i);
    short4v h, l;
    short th, tl;
    split2(v.x, th, tl); h.x = th; l.x = tl;
    split2(v.y, th, tl); h.y = th; l.y = tl;
    split2(v.z, th, tl); h.z = th; l.z = tl;
    split2(v.w, th, tl); h.w = th; l.w = tl;
    *(short4v*)(hi + i) = h;
    *(short4v*)(lo + i) = l;
  }
}

// ---------------- f32 -> bf16 (for out_w only) ----------------
__global__ void k_cvt(const float* __restrict__ in, short* __restrict__ out, int n){
  int i = (blockIdx.x * blockDim.x + threadIdx.x) * 4;
  if (i < n){
    float4 v = *(const float4*)(in + i);
    short4v o; o.x = f2b(v.x); o.y = f2b(v.y); o.z = f2b(v.z); o.w = f2b(v.w);
    *(short4v*)(out + i) = o;
  }
}

// ---------------- split GEMM-NT (3-pass): qkgv = X W^T + b, fused activations ----------------
__global__ __launch_bounds__(256) void k_gemm1(
    const short* __restrict__ Ah, const short* __restrict__ Al,
    const short* __restrict__ Bh, const short* __restrict__ Bl,
    const float* __restrict__ bias,
    float* __restrict__ q_o, float* __restrict__ kg_o,
    float* __restrict__ lg_o, float* __restrict__ vv_o)
{
  const int Kd = 512;
  __shared__ __align__(16) short Ash[128][40], Asl[128][40];
  __shared__ __align__(16) short Bsh[64][40],  Bsl[64][40];
  const int m0 = blockIdx.x * 128, n0 = blockIdx.y * 64;
  const int tid = threadIdx.x, lane = tid & 63, w = tid >> 6;
  const int wr = w >> 1, wc = w & 1;
  const int coll = lane & 15, rq = lane >> 4;
  f32x4 acc[4][2];
#pragma unroll
  for (int i = 0; i < 4; i++)
#pragma unroll
    for (int j = 0; j < 2; j++) acc[i][j] = (f32x4){0.f,0.f,0.f,0.f};

  const int ar = tid >> 1, ac = (tid & 1) * 16;
  const int br = tid >> 2, bc = (tid & 3) * 8;

  for (int k0 = 0; k0 < Kd; k0 += 32){
    __syncthreads();
    { size_t g = (size_t)(m0 + ar) * Kd + k0 + ac;
      *(bf16x8*)&Ash[ar][ac]     = *(const bf16x8*)(Ah + g);
      *(bf16x8*)&Ash[ar][ac + 8] = *(const bf16x8*)(Ah + g + 8);
      *(bf16x8*)&Asl[ar][ac]     = *(const bf16x8*)(Al + g);
      *(bf16x8*)&Asl[ar][ac + 8] = *(const bf16x8*)(Al + g + 8); }
    { size_t g = (size_t)(n0 + br) * Kd + k0 + bc;
      *(bf16x8*)&Bsh[br][bc] = *(const bf16x8*)(Bh + g);
      *(bf16x8*)&Bsl[br][bc] = *(const bf16x8*)(Bl + g); }
    __syncthreads();
    bf16x8 ah[4], al[4], bh[2], bl[2];
#pragma unroll
    for (int mi = 0; mi < 4; mi++){
      ah[mi] = *(const bf16x8*)&Ash[wr*64 + mi*16 + coll][rq*8];
      al[mi] = *(const bf16x8*)&Asl[wr*64 + mi*16 + coll][rq*8];
    }
#pragma unroll
    for (int ni = 0; ni < 2; ni++){
      bh[ni] = *(const bf16x8*)&Bsh[wc*32 + ni*16 + coll][rq*8];
      bl[ni] = *(const bf16x8*)&Bsl[wc*32 + ni*16 + coll][rq*8];
    }
#pragma unroll
    for (int mi = 0; mi < 4; mi++)
#pragma unroll
      for (int ni = 0; ni < 2; ni++){
        acc[mi][ni] = MFMA(ah[mi], bh[ni], acc[mi][ni]);
        acc[mi][ni] = MFMA(ah[mi], bl[ni], acc[mi][ni]);
        acc[mi][ni] = MFMA(al[mi], bh[ni], acc[mi][ni]);
      }
  }
#pragma unroll
  for (int mi = 0; mi < 4; mi++)
#pragma unroll
  for (int ni = 0; ni < 2; ni++){
    int gn = n0 + wc*32 + ni*16 + coll;
    float bsv = bias[gn];
    int sec = gn >> 7, jj = gn & 127;
#pragma unroll
    for (int r = 0; r < 4; r++){
      int gm = m0 + wr*64 + mi*16 + rq*4 + r;
      float v = acc[mi][ni][r] + bsv;
      size_t idx = (size_t)gm * 128 + jj;
      if (sec == 0)      q_o[idx] = v;
      else if (sec == 1) kg_o[idx] = 1.f / (1.f + __expf(-v));
      else if (sec == 2) lg_o[idx] = (v > 0.f) ? -log1pf(__expf(-v)) : (v - log1pf(__expf(v)));
      else               vv_o[idx] = tanhf(v);
    }
  }
}

// ---------------- per-(b,chunk) prep: f64 cum-log-gates, split q~/k~/k^T/V^T ----------------
__global__ __launch_bounds__(128) void k_prep(
  const float* __restrict__ q_f, const float* __restrict__ kg_f,
  const float* __restrict__ lg_f, const float* __restrict__ vv_f,
  short* __restrict__ qth, short* __restrict__ qtl,
  short* __restrict__ kth, short* __restrict__ ktl,
  short* __restrict__ khTh, short* __restrict__ khTl,
  short* __restrict__ vvTh, short* __restrict__ vvTl,
  float* __restrict__ Dend)
{
  const int bc = blockIdx.x;                 // b*64 + ck
  const int kx = threadIdx.x;                // 0..127
  const size_t base = ((size_t)(bc >> 6) * 2048 + (size_t)(bc & 63) * 32) * 128 + kx;
  double L[32];
  double Lr = 0.0;
#pragma unroll
  for (int s = 0; s < 32; s++){
    size_t idx = base + (size_t)s * 128;
    Lr += (double)lg_f[idx];
    L[s] = Lr;
    float lam  = __expf((float)Lr);
    float ilam = __expf((float)(-Lr));
    short h, l;
    split2(q_f[idx] * lam, h, l);  qth[idx] = h; qtl[idx] = l;   // q~ = q * Lambda
    split2(kg_f[idx] * ilam, h, l); kth[idx] = h; ktl[idx] = l;  // k~ = k / Lambda
  }
  const double Lend = Lr;
  Dend[(size_t)bc * 128 + kx] = (float)exp(Lend);   // f64 exp: decay chain stays accurate
  __align__(16) short bufh[32], bufl[32];
#pragma unroll
  for (int s = 0; s < 32; s++){
    size_t idx = base + (size_t)s * 128;
    short h, l;
    split2(kg_f[idx] * __expf((float)(Lend - L[s])), h, l);   // k^ <= k
    bufh[s] = h; bufl[s] = l;
  }
  { short* dh = khTh + ((size_t)bc * 128 + kx) * 32;
    short* dl = khTl + ((size_t)bc * 128 + kx) * 32;
#pragma unroll
    for (int i = 0; i < 32; i += 8){
      *(bf16x8*)(dh + i) = *(const bf16x8*)(bufh + i);
      *(bf16x8*)(dl + i) = *(const bf16x8*)(bufl + i);
    } }
#pragma unroll
  for (int s = 0; s < 32; s++){
    short h, l;
    split2(vv_f[base + (size_t)s * 128], h, l);
    bufh[s] = h; bufl[s] = l;
  }
  { short* dh = vvTh + ((size_t)bc * 128 + kx) * 32;
    short* dl = vvTl + ((size_t)bc * 128 + kx) * 32;
#pragma unroll
    for (int i = 0; i < 32; i += 8){
      *(bf16x8*)(dh + i) = *(const bf16x8*)(bufh + i);
      *(bf16x8*)(dl + i) = *(const bf16x8*)(bufl + i);
    } }
}

// ---------------- state scan over chunks, grid = B*64 single-wave blocks ----------------
__global__ __launch_bounds__(64) void k_scan(
  const short* __restrict__ khTh, const short* __restrict__ khTl,
  const short* __restrict__ vvTh, const short* __restrict__ vvTl,
  const float* __restrict__ Dend, const float* __restrict__ cell0,
  short* __restrict__ sth, short* __restrict__ stl, float* __restrict__ Cfin)
{
  const int blk = blockIdx.x;
  const int b = blk >> 6, tile = blk & 63;
  const int kt = tile >> 3, vt = tile & 7;
  const int lane = threadIdx.x & 63;
  const int coll = lane & 15, rq = lane >> 4;
  const int kcol = kt*16 + coll;
  const int vrow0 = vt*16 + rq*4;
  const size_t cb0 = (size_t)b * 64;

  f32x4 acc;
#pragma unroll
  for (int r = 0; r < 4; r++)
    acc[r] = cell0[((size_t)b*128 + kcol)*128 + vrow0 + r];

  size_t gv = (cb0*128 + vt*16 + coll)*32 + rq*8;
  size_t gk = (cb0*128 + kt*16 + coll)*32 + rq*8;
  bf16x8 avh = *(const bf16x8*)(vvTh + gv);
  bf16x8 avl = *(const bf16x8*)(vvTl + gv);
  bf16x8 bkh = *(const bf16x8*)(khTh + gk);
  bf16x8 bkl = *(const bf16x8*)(khTl + gk);
  float d = Dend[cb0*128 + kcol];

  for (int ck = 0; ck < 64; ck++){
    const size_t cb = cb0 + ck;
    const size_t cbn = cb0 + (ck < 63 ? ck + 1 : ck);
    size_t ngv = (cbn*128 + vt*16 + coll)*32 + rq*8;
    size_t ngk = (cbn*128 + kt*16 + coll)*32 + rq*8;
    bf16x8 navh = *(const bf16x8*)(vvTh + ngv);
    bf16x8 navl = *(const bf16x8*)(vvTl + ngv);
    bf16x8 nbkh = *(const bf16x8*)(khTh + ngk);
    bf16x8 nbkl = *(const bf16x8*)(khTl + ngk);
    float nd = Dend[cbn*128 + kcol];
    {
      size_t sb = (cb*128 + vrow0)*128 + kcol;
#pragma unroll
      for (int r = 0; r < 4; r++){
        short h, l; split2(acc[r], h, l);
        sth[sb + (size_t)r*128] = h;
        stl[sb + (size_t)r*128] = l;
      }
    }
#pragma unroll
    for (int r = 0; r < 4; r++) acc[r] *= d;
    acc = MFMA(avh, bkh, acc);
    acc = MFMA(avh, bkl, acc);
    acc = MFMA(avl, bkh, acc);
    avh = navh; avl = navl; bkh = nbkh; bkl = nbkl; d = nd;
  }
  *(f32x4*)(Cfin + ((size_t)b*128 + kcol)*128 + vrow0) = acc;
}

// ---------------- per-(b,chunk) outputs (3-pass split): o^T = C^T q~^T + V^T A^T ----------------
__global__ __launch_bounds__(256) void k_chunkout(
  const short* __restrict__ qth, const short* __restrict__ qtl,
  const short* __restrict__ kth, const short* __restrict__ ktl,
  const short* __restrict__ vvTh, const short* __restrict__ vvTl,
  const short* __restrict__ sth, const short* __restrict__ stl,
  short* __restrict__ ovT, short* __restrict__ ovc,
  short* __restrict__ ovqh, short* __restrict__ ovql)
{
  __shared__ __align__(16) short ATh[32][40], ATl[32][40];
  const int bc = blockIdx.x;
  const int b = bc >> 6, ck = bc & 63;
  const int tid = threadIdx.x, lane = tid & 63, w = tid >> 6;
  const int coll = lane & 15, rq = lane >> 4;
  const size_t tbase = (size_t)b * 2048 + (size_t)ck * 32;
  {
    const int si = w >> 1, ti = w & 1;
    f32x4 aA = (f32x4){0.f,0.f,0.f,0.f};
#pragma unroll
    for (int kit = 0; kit < 4; kit++){
      size_t ga = (tbase + si*16 + coll) * 128 + kit*32 + rq*8;
      size_t gb = (tbase + ti*16 + coll) * 128 + kit*32 + rq*8;
      bf16x8 a3h = *(const bf16x8*)(kth + ga), a3l = *(const bf16x8*)(ktl + ga);
      bf16x8 b3h = *(const bf16x8*)(qth + gb), b3l = *(const bf16x8*)(qtl + gb);
      aA = MFMA(a3h, b3h, aA);
      aA = MFMA(a3h, b3l, aA);
      aA = MFMA(a3l, b3h, aA);
    }
#pragma unroll
    for (int r = 0; r < 4; r++){
      int s = si*16 + rq*4 + r, t = ti*16 + coll;
      float val = (s <= t) ? aA[r] : 0.f;     // causal mask, diag kept
      short h, l; split2(val, h, l);
      ATh[t][s] = h; ATl[t][s] = l;
    }
  }
  __syncthreads();
  const int vb = w * 32;
  f32x4 o[2][2];
#pragma unroll
  for (int vi = 0; vi < 2; vi++)
#pragma unroll
    for (int ti = 0; ti < 2; ti++) o[vi][ti] = (f32x4){0.f,0.f,0.f,0.f};
#pragma unroll
  for (int kit = 0; kit < 4; kit++){
    bf16x8 aCh[2], aCl[2], bqh[2], bql[2];
#pragma unroll
    for (int vi = 0; vi < 2; vi++){
      size_t g = ((size_t)bc * 128 + vb + vi*16 + coll) * 128 + kit*32 + rq*8;
      aCh[vi] = *(const bf16x8*)(sth + g);
      aCl[vi] = *(const bf16x8*)(stl + g);
    }
#pragma unroll
    for (int ti = 0; ti < 2; ti++){
      size_t g = (tbase + ti*16 + coll) * 128 + kit*32 + rq*8;
      bqh[ti] = *(const bf16x8*)(qth + g);
      bql[ti] = *(const bf16x8*)(qtl + g);
    }
#pragma unroll
    for (int vi = 0; vi < 2; vi++)
#pragma unroll
      for (int ti = 0; ti < 2; ti++){
        o[vi][ti] = MFMA(aCh[vi], bqh[ti], o[vi][ti]);
        o[vi][ti] = MFMA(aCh[vi], bql[ti], o[vi][ti]);
        o[vi][ti] = MFMA(aCl[vi], bqh[ti], o[vi][ti]);
      }
  }
  {
    bf16x8 a2h[2], a2l[2], b2h[2], b2l[2];
#pragma unroll
    for (int vi = 0; vi < 2; vi++){
      size_t g = ((size_t)bc * 128 + vb + vi*16 + coll) * 32 + rq*8;
      a2h[vi] = *(const bf16x8*)(vvTh + g);
      a2l[vi] = *(const bf16x8*)(vvTl + g);
    }
#pragma unroll
    for (int ti = 0; ti < 2; ti++){
      b2h[ti] = *(const bf16x8*)&ATh[ti*16 + coll][rq*8];
      b2l[ti] = *(const bf16x8*)&ATl[ti*16 + coll][rq*8];
    }
#pragma unroll
    for (int vi = 0; vi < 2; vi++)
#pragma unroll
      for (int ti = 0; ti < 2; ti++){
        o[vi][ti] = MFMA(a2h[vi], b2h[ti], o[vi][ti]);
        o[vi][ti] = MFMA(a2h[vi], b2l[ti], o[vi][ti]);
        o[vi][ti] = MFMA(a2l[vi], b2h[ti], o[vi][ti]);
      }
  }
#pragma unroll
  for (int vi = 0; vi < 2; vi++)
#pragma unroll
  for (int ti = 0; ti < 2; ti++)
#pragma unroll
  for (int r = 0; r < 4; r++){
    int v = vb + vi*16 + rq*4 + r;
    int tl = ti*16 + coll;
    float val = o[vi][ti][r];
    short h, l; split2(val, h, l);
    ovT[((size_t)b * 128 + v) * 2048 + (size_t)ck * 32 + tl] = h;  // [b][v][t] bf16 (PV operand)
    ovc[(tbase + tl) * 256 + v] = h;                                // [b][t][0:128] bf16
    ovqh[(tbase + tl) * 128 + v] = h;                               // split ov for scores
    ovql[(tbase + tl) * 128 + v] = l;
  }
}

// ---------------- causal softmax attention: flash-decoding split-S (P=8 x 256) ----------------
// grid (32, 4, 8) = (qtile, b, partition). Partials: m/l f32, oa bf16 per (b,t,p).
__global__ __launch_bounds__(256) void k_attn(
  const short* __restrict__ ovqh, const short* __restrict__ ovql,
  const short* __restrict__ ovT,
  float* __restrict__ m_part, float* __restrict__ l_part,
  short* __restrict__ oa_part)
{
  const int qi = blockIdx.x, b = blockIdx.y, p = blockIdx.z;
  const int qbase = qi * 64;
  const int ps = p * 256;
  const size_t obase = (size_t)b * 2048;
  const int tid = threadIdx.x;
  if (ps > qbase + 63){
    // inactive (b,qtile,partition): mark empty rows so k_comb skips them
    if (tid < 64) l_part[((obase + qbase + tid) << 3) + p] = 0.f;
    return;
  }
  __shared__ __align__(16) short P[4][16][40];
  const int lane = tid & 63, w = tid >> 6;
  const int coll = lane & 15, rq = lane >> 4;
  const int tw = qbase + w * 16;
  bf16x8 qfh[4], qfl[4];
#pragma unroll
  for (int kit = 0; kit < 4; kit++){
    size_t g = (obase + tw + coll) * 128 + kit*32 + rq*8;
    qfh[kit] = *(const bf16x8*)(ovqh + g);
    qfl[kit] = *(const bf16x8*)(ovql + g);
  }
  float m[4], l[4];
  f32x4 oa[8];
#pragma unroll
  for (int r = 0; r < 4; r++){ m[r] = -1e30f; l[r] = 0.f; }
#pragma unroll
  for (int df = 0; df < 8; df++) oa[df] = (f32x4){0.f,0.f,0.f,0.f};
  const int send = min(tw + 15, ps + 255);
  for (int s0 = ps; s0 <= send; s0 += 32){
    // scores: 3 independent MFMA chains per 16-col slab (hh, hl, lh; ll dropped ~2^-18)
    f32x4 sc[2];
#pragma unroll
    for (int sf = 0; sf < 2; sf++){
      bf16x8 kh[4], kl[4];
#pragma unroll
      for (int kit = 0; kit < 4; kit++){
        size_t g = (obase + s0 + sf*16 + coll) * 128 + kit*32 + rq*8;
        kh[kit] = *(const bf16x8*)(ovqh + g);
        kl[kit] = *(const bf16x8*)(ovql + g);
      }
      f32x4 c0 = (f32x4){0.f,0.f,0.f,0.f};
      f32x4 c1 = (f32x4){0.f,0.f,0.f,0.f};
      f32x4 c2 = (f32x4){0.f,0.f,0.f,0.f};
#pragma unroll
      for (int kit = 0; kit < 4; kit++){
        c0 = MFMA(qfh[kit], kh[kit], c0);
        c1 = MFMA(qfh[kit], kl[kit], c1);
        c2 = MFMA(qfl[kit], kh[kit], c2);
      }
      sc[sf] = c0 + c1 + c2;
    }
    // V tile loads (independent; overlap with softmax)
    bf16x8 vf[8];
#pragma unroll
    for (int df = 0; df < 8; df++)
      vf[df] = *(const bf16x8*)(ovT + ((size_t)b*128 + df*16 + coll)*2048 + s0 + rq*8);
    // partition-local online softmax
#pragma unroll
    for (int r = 0; r < 4; r++){
      int trow = tw + rq*4 + r;
      float s0v = (s0 + coll      <= trow) ? sc[0][r] : -1e30f;
      float s1v = (s0 + 16 + coll <= trow) ? sc[1][r] : -1e30f;
      float mx = fmaxf(s0v, s1v);
#pragma unroll
      for (int d = 1; d < 16; d <<= 1) mx = fmaxf(mx, __shfl_xor(mx, d));
      float mn = fmaxf(m[r], mx);
      float scale = __expf(m[r] - mn);
      float p0 = __expf(s0v - mn);
      float p1 = __expf(s1v - mn);
      float rs = p0 + p1;
#pragma unroll
      for (int d = 1; d < 16; d <<= 1) rs += __shfl_xor(rs, d);
      l[r] = l[r] * scale + rs;
      m[r] = mn;
#pragma unroll
      for (int df = 0; df < 8; df++) oa[df][r] *= scale;
      P[w][rq*4 + r][coll]      = f2b(p0);
      P[w][rq*4 + r][16 + coll] = f2b(p1);
    }
    bf16x8 pf = *(const bf16x8*)&P[w][coll][rq*8];
#pragma unroll
    for (int df = 0; df < 8; df++)
      oa[df] = MFMA(pf, vf[df], oa[df]);
  }
  // write partials: m/l (f32, one lane per row) + oa (bf16)
#pragma unroll
  for (int r = 0; r < 4; r++){
    int t = tw + rq*4 + r;
    size_t idx8 = ((obase + t) << 3) + p;
    if (coll == 0){ m_part[idx8] = m[r]; l_part[idx8] = l[r]; }
#pragma unroll
    for (int df = 0; df < 8; df++)
      oa_part[idx8*128 + df*16 + coll] = f2b(oa[df][r]);
  }
}

// ---------------- LSE combine of 8 partials -> ctx (ovc[...,128:256]) ----------------
__global__ __launch_bounds__(256) void k_comb(
  const float* __restrict__ m_part, const float* __restrict__ l_part,
  const short* __restrict__ oa_part, short* __restrict__ ovc)
{
  const int blk = blockIdx.x;          // b*32 + qi
  const int b = blk >> 5, qi = blk & 31;
  const int row = threadIdx.x >> 2, cg = threadIdx.x & 3;
  const int t = qi*64 + row;
  const size_t base8 = ((size_t)b*2048 + t) * 8;
  float mv[8], lv[8];
#pragma unroll
  for (int p = 0; p < 8; p++){ mv[p] = m_part[base8+p]; lv[p] = l_part[base8+p]; }
  float M = -3e38f;
#pragma unroll
  for (int p = 0; p < 8; p++) if (lv[p] > 0.f) M = fmaxf(M, mv[p]);
  float L = 0.f, wgt[8];
#pragma unroll
  for (int p = 0; p < 8; p++){
    wgt[p] = (lv[p] > 0.f) ? __expf(mv[p] - M) : 0.f;
    L += lv[p] * wgt[p];
  }
  const float inv = 1.f / L;
  const int v0 = cg * 32;
  float acc[32];
#pragma unroll
  for (int j = 0; j < 32; j++) acc[j] = 0.f;
#pragma unroll
  for (int p = 0; p < 8; p++){
    if (lv[p] > 0.f){
      const short* src = oa_part + (base8 + p)*128 + v0;
#pragma unroll
      for (int jo = 0; jo < 32; jo += 8){
        bf16x8 x = *(const bf16x8*)(src + jo);
#pragma unroll
        for (int j = 0; j < 8; j++) acc[jo+j] += b2f(x[j]) * wgt[p];
      }
    }
  }
  short* dst = ovc + ((size_t)b*2048 + t)*256 + 128 + v0;
#pragma unroll
  for (int jo = 0; jo < 32; jo += 8){
    bf16x8 o;
#pragma unroll
    for (int j = 0; j < 8; j++) o[j] = f2b(acc[jo+j] * inv);
    *(bf16x8*)(dst + jo) = o;
  }
}

// ---------------- output GEMM (bf16 NT): out = concat(ov,ctx) @ OW^T + b ----------------
__global__ __launch_bounds__(256) void k_gemm0(
  const short* __restrict__ A, const short* __restrict__ Bw,
  const float* __restrict__ bias, float* __restrict__ out)
{
  const int Kd = 256, N = 512;
  __shared__ __align__(16) short As[128][40];
  __shared__ __align__(16) short Bs[64][40];
  const int m0 = blockIdx.x * 128, n0 = blockIdx.y * 64;
  const int tid = threadIdx.x, lane = tid & 63, w = tid >> 6;
  const int wr = w >> 1, wc = w & 1;
  const int coll = lane & 15, rq = lane >> 4;
  f32x4 acc[4][2];
#pragma unroll
  for (int i = 0; i < 4; i++)
#pragma unroll
    for (int j = 0; j < 2; j++) acc[i][j] = (f32x4){0.f,0.f,0.f,0.f};
  const int ar = tid >> 1, ac = (tid & 1) * 16;
  const int br = tid >> 2, bc = (tid & 3) * 8;
  for (int k0 = 0; k0 < Kd; k0 += 32){
    __syncthreads();
    { const short* g = A + (size_t)(m0 + ar) * Kd + k0 + ac;
      *(bf16x8*)&As[ar][ac]     = *(const bf16x8*)g;
      *(bf16x8*)&As[ar][ac + 8] = *(const bf16x8*)(g + 8); }
    { const short* g = Bw + (size_t)(n0 + br) * Kd + k0 + bc;
      *(bf16x8*)&Bs[br][bc] = *(const bf16x8*)g; }
    __syncthreads();
    bf16x8 a[4], b[2];
#pragma unroll
    for (int mi = 0; mi < 4; mi++) a[mi] = *(const bf16x8*)&As[wr*64 + mi*16 + coll][rq*8];
#pragma unroll
    for (int ni = 0; ni < 2; ni++) b[ni] = *(const bf16x8*)&Bs[wc*32 + ni*16 + coll][rq*8];
#pragma unroll
    for (int mi = 0; mi < 4; mi++)
#pragma unroll
      for (int ni = 0; ni < 2; ni++) acc[mi][ni] = MFMA(a[mi], b[ni], acc[mi][ni]);
  }
#pragma unroll
  for (int mi = 0; mi < 4; mi++)
#pragma unroll
  for (int ni = 0; ni < 2; ni++){
    int gn = n0 + wc*32 + ni*16 + coll;
    float bsv = bias[gn];
#pragma unroll
    for (int r = 0; r < 4; r++){
      int gm = m0 + wr*64 + mi*16 + rq*4 + r;
      out[(size_t)gm * N + gn] = acc[mi][ni][r] + bsv;
    }
  }
}

// ---------------- host launch ----------------
extern "C" void kernel_launch(void* const* d_in, const int* in_sizes, int n_in,
                              void* d_out, int out_size, void* d_ws, size_t ws_size,
                              hipStream_t stream){
  const float* hidden = (const float*)d_in[0];   // (4,2048,512)
  const float* cell0  = (const float*)d_in[1];   // (4,128,128)
  const float* projw  = (const float*)d_in[2];   // (512,512)
  const float* projb  = (const float*)d_in[3];   // (512,)
  const float* outw   = (const float*)d_in[4];   // (512,256)
  const float* outb   = (const float*)d_in[5];   // (512,)
  float* out = (float*)d_out;

  char* ws = (char*)d_ws;
  size_t off = 0;
  auto alloc = [&](size_t bytes) -> void* {
    void* p = ws + off;
    off += (bytes + 255) & ~(size_t)255;
    return p;
  };
  // Arena A: X split (phase 1) -> ov buffers (phase 2). 16.78 MB.
  short* Xh   = (short*)alloc(8192ULL * 512 * 2);
  short* Xl   = (short*)alloc(8192ULL * 512 * 2);
  short* ovqh = Xh;                       // 8192*128 shorts
  short* ovql = Xh + 1048576;
  short* ovT  = Xh + 2097152;             // 4*128*2048 shorts
  short* ovc  = Xh + 3145728;             // 8192*256 shorts
  // Arena B: q/kg/lg/vv f32 (phase 1) -> states hi/lo (scan/chunkout) -> oa partials (attn). 16.78 MB.
  float* q_f  = (float*)alloc(8192ULL * 128 * 4);
  float* kg_f = (float*)alloc(8192ULL * 128 * 4);
  float* lg_f = (float*)alloc(8192ULL * 128 * 4);
  float* vv_f = (float*)alloc(8192ULL * 128 * 4);
  short* sth  = (short*)q_f;              // 256*128*128 shorts
  short* stl  = sth + 4194304;
  short* oa_part = (short*)q_f;           // 4*2048*8*128 shorts (= whole arena B)
  // Persistent
  short* Wh   = (short*)alloc(512ULL * 512 * 2);
  short* Wl   = (short*)alloc(512ULL * 512 * 2);
  short* OWbf = (short*)alloc(512ULL * 256 * 2);
  short* qth  = (short*)alloc(8192ULL * 128 * 2);
  short* qtl  = (short*)alloc(8192ULL * 128 * 2);
  short* kth  = (short*)alloc(8192ULL * 128 * 2);
  short* ktl  = (short*)alloc(8192ULL * 128 * 2);
  short* khTh = (short*)alloc(256ULL * 128 * 32 * 2);
  short* khTl = (short*)alloc(256ULL * 128 * 32 * 2);
  short* vvTh = (short*)alloc(256ULL * 128 * 32 * 2);
  short* vvTl = (short*)alloc(256ULL * 128 * 32 * 2);
  float* Dend = (float*)alloc(256ULL * 128 * 4);
  float* m_part = (float*)alloc(4ULL * 2048 * 8 * 4);
  float* l_part = (float*)alloc(4ULL * 2048 * 8 * 4);

  k_split<<<4096, 256, 0, stream>>>(hidden, Xh, Xl, 8192 * 512);
  k_split<<<256,  256, 0, stream>>>(projw,  Wh, Wl, 512 * 512);
  k_cvt<<<128, 256, 0, stream>>>(outw, OWbf, 512 * 256);

  k_gemm1<<<dim3(64, 8), 256, 0, stream>>>(Xh, Xl, Wh, Wl, projb, q_f, kg_f, lg_f, vv_f);
  k_prep<<<256, 128, 0, stream>>>(q_f, kg_f, lg_f, vv_f,
                                  qth, qtl, kth, ktl, khTh, khTl, vvTh, vvTl, Dend);
  k_scan<<<256, 64, 0, stream>>>(khTh, khTl, vvTh, vvTl, Dend, cell0,
                                 sth, stl, out + 8192ULL * 512);
  k_chunkout<<<256, 256, 0, stream>>>(qth, qtl, kth, ktl, vvTh, vvTl, sth, stl,
                                      ovT, ovc, ovqh, ovql);
  k_attn<<<dim3(32, 4, 8), 256, 0, stream>>>(ovqh, ovql, ovT, m_part, l_part, oa_part);
  k_comb<<<128, 256, 0, stream>>>(m_part, l_part, oa_part, ovc);
  k_gemm0<<<dim3(64, 8), 256, 0, stream>>>(ovc, OWbf, outb, out);
}

// Round 6
// 293.763 us; speedup vs baseline: 1.9213x; 1.0001x over previous
//
#include <hip/hip_runtime.h>
#include <hip/hip_bf16.h>

// SimpleRNN: chunked gated-linear-attention scan + exact causal softmax attention + projections.
// B=4, T=2048, H=512, K=V=128, O=512. Chunk S=32, NC=64.
// Precision: split-bf16 (hi+lo) through the whole ov pipeline (scores amplify ov err ~5000x).
// R3: k_scan -> 256 single-wave blocks. R5: k_attn flash-decoding split-S (P=8, LSE combine).
// R6: both GEMMs rewritten m97-style: virtual-K segment fold, BK=64, global_load_lds(16B),
//     XOR-swizzled LDS (T2, source-side permutation), single buffer, 24KB LDS.

typedef __attribute__((ext_vector_type(8))) short bf16x8;
typedef __attribute__((ext_vector_type(4))) float f32x4;
typedef __attribute__((ext_vector_type(4))) short short4v;

#define MFMA(a,b,c) __builtin_amdgcn_mfma_f32_16x16x32_bf16(a,b,c,0,0,0)

__device__ __forceinline__ short f2b(float x){
  union { float f; unsigned u; } v; v.f = x;
  unsigned r = v.u + 0x7fffu + ((v.u >> 16) & 1u);   // RTNE
  return (short)(r >> 16);
}
__device__ __forceinline__ float b2f(short h){
  union { unsigned u; float f; } v;
  v.u = ((unsigned)(unsigned short)h) << 16;
  return v.f;
}
__device__ __forceinline__ void split2(float x, short& h, short& l){
  h = f2b(x);
  l = f2b(x - b2f(h));
}
// async global->LDS, 16B per lane; LDS dest must be wave-uniform base + lane*16 (linear).
__device__ __forceinline__ void gload16(const void* g, void* l){
  __builtin_amdgcn_global_load_lds(
    (__attribute__((address_space(1))) unsigned int*)(void*)(g),
    (__attribute__((address_space(3))) unsigned int*)(l), 16, 0, 0);
}

// ---------------- f32 -> (hi, lo) bf16 split ----------------
__global__ void k_split(const float* __restrict__ in, short* __restrict__ hi,
                        short* __restrict__ lo, int n){
  int i = (blockIdx.x * blockDim.x + threadIdx.x) * 4;
  if (i < n){
    float4 v = *(const float4*)(in + i);
    short4v h, l;
    short th, tl;
    split2(v.x, th, tl); h.x = th; l.x = tl;
    split2(v.y, th, tl); h.y = th; l.y = tl;
    split2(v.z, th, tl); h.z = th; l.z = tl;
    split2(v.w, th, tl); h.w = th; l.w = tl;
    *(short4v*)(hi + i) = h;
    *(short4v*)(lo + i) = l;
  }
}

// ---------------- f32 -> bf16 (for out_w only) ----------------
__global__ void k_cvt(const float* __restrict__ in, short* __restrict__ out, int n){
  int i = (blockIdx.x * blockDim.x + threadIdx.x) * 4;
  if (i < n){
    float4 v = *(const float4*)(in + i);
    short4v o; o.x = f2b(v.x); o.y = f2b(v.y); o.z = f2b(v.z); o.w = f2b(v.w);
    *(short4v*)(out + i) = o;
  }
}

// ---------------- split GEMM-NT (virtual K=1536): qkgv = X W^T + b, fused activations ------
// BM=128, BN=64, BK=64; segments: [Ah.Bh | Ah.Bl | Al.Bh]. grid (64, 8), 256 thr.
__global__ __launch_bounds__(256) void k_gemm1(
    const short* __restrict__ Ah, const short* __restrict__ Al,
    const short* __restrict__ Bh, const short* __restrict__ Bl,
    const float* __restrict__ bias,
    float* __restrict__ q_o, float* __restrict__ kg_o,
    float* __restrict__ lg_o, float* __restrict__ vv_o)
{
  __shared__ __align__(16) short At[128*64];
  __shared__ __align__(16) short Bt[64*64];
  const int m0 = blockIdx.x * 128;
  const int ny = blockIdx.y;                 // n0 = ny*64
  const int tid = threadIdx.x, lane = tid & 63, w = tid >> 6;
  const int wr = w >> 1, wc = w & 1;
  const int coll = lane & 15, rq = lane >> 4;
  f32x4 acc[4][2];
#pragma unroll
  for (int i = 0; i < 4; i++)
#pragma unroll
    for (int j = 0; j < 2; j++) acc[i][j] = (f32x4){0.f,0.f,0.f,0.f};

  for (int step = 0; step < 24; ++step){
    const int seg = step >> 3;
    const int k0 = (step & 7) * 64;
    const short* Asrc = (seg < 2) ? Ah : Al;
    const short* Bsrc = (seg == 1) ? Bl : Bh;
    __syncthreads();                          // prior reads done before overwrite
#pragma unroll
    for (int t = 0; t < 4; ++t){              // A: 128x64 shorts = 16KB
      int ci = t*256 + tid;
      int row = ci >> 3;
      int cs = (ci & 7) ^ (row & 7);          // source-side swizzle (involution)
      gload16(Asrc + (size_t)(m0 + row)*512 + k0 + cs*8, At + ci*8);
    }
#pragma unroll
    for (int t = 0; t < 2; ++t){              // B: 64x64 shorts = 8KB
      int ci = t*256 + tid;
      int row = ci >> 3;
      int cs = (ci & 7) ^ (row & 7);
      gload16(Bsrc + (size_t)(ny*64 + row)*512 + k0 + cs*8, Bt + ci*8);
    }
    __syncthreads();                          // vmcnt(0) drain by compiler
#pragma unroll
    for (int kk = 0; kk < 2; ++kk){
      bf16x8 a[4], b[2];
#pragma unroll
      for (int mi = 0; mi < 4; mi++){
        int ar = wr*64 + mi*16 + coll;
        a[mi] = *(const bf16x8*)&At[ar*64 + (((kk*4+rq) ^ (ar & 7))*8)];
      }
#pragma unroll
      for (int ni = 0; ni < 2; ni++){
        int br = wc*32 + ni*16 + coll;
        b[ni] = *(const bf16x8*)&Bt[br*64 + (((kk*4+rq) ^ (br & 7))*8)];
      }
#pragma unroll
      for (int mi = 0; mi < 4; mi++)
#pragma unroll
        for (int ni = 0; ni < 2; ni++)
          acc[mi][ni] = MFMA(a[mi], b[ni], acc[mi][ni]);
    }
  }
  const int sec = ny >> 1;                    // uniform per block
  const int jb  = (ny & 1) * 64;
#pragma unroll
  for (int mi = 0; mi < 4; mi++)
#pragma unroll
  for (int ni = 0; ni < 2; ni++){
    int gl = wc*32 + ni*16 + coll;            // 0..63
    float bsv = bias[ny*64 + gl];
    int jj = jb + gl;
#pragma unroll
    for (int r = 0; r < 4; r++){
      int gm = m0 + wr*64 + mi*16 + rq*4 + r;
      float v = acc[mi][ni][r] + bsv;
      size_t idx = (size_t)gm * 128 + jj;
      if (sec == 0)      q_o[idx] = v;
      else if (sec == 1) kg_o[idx] = 1.f / (1.f + __expf(-v));
      else if (sec == 2) lg_o[idx] = (v > 0.f) ? -log1pf(__expf(-v)) : (v - log1pf(__expf(v)));
      else               vv_o[idx] = tanhf(v);
    }
  }
}

// ---------------- per-(b,chunk) prep: f64 cum-log-gates, split q~/k~/k^T/V^T ----------------
__global__ __launch_bounds__(128) void k_prep(
  const float* __restrict__ q_f, const float* __restrict__ kg_f,
  const float* __restrict__ lg_f, const float* __restrict__ vv_f,
  short* __restrict__ qth, short* __restrict__ qtl,
  short* __restrict__ kth, short* __restrict__ ktl,
  short* __restrict__ khTh, short* __restrict__ khTl,
  short* __restrict__ vvTh, short* __restrict__ vvTl,
  float* __restrict__ Dend)
{
  const int bc = blockIdx.x;                 // b*64 + ck
  const int kx = threadIdx.x;                // 0..127
  const size_t base = ((size_t)(bc >> 6) * 2048 + (size_t)(bc & 63) * 32) * 128 + kx;
  double L[32];
  double Lr = 0.0;
#pragma unroll
  for (int s = 0; s < 32; s++){
    size_t idx = base + (size_t)s * 128;
    Lr += (double)lg_f[idx];
    L[s] = Lr;
    float lam  = __expf((float)Lr);
    float ilam = __expf((float)(-Lr));
    short h, l;
    split2(q_f[idx] * lam, h, l);  qth[idx] = h; qtl[idx] = l;   // q~ = q * Lambda
    split2(kg_f[idx] * ilam, h, l); kth[idx] = h; ktl[idx] = l;  // k~ = k / Lambda
  }
  const double Lend = Lr;
  Dend[(size_t)bc * 128 + kx] = (float)exp(Lend);
  __align__(16) short bufh[32], bufl[32];
#pragma unroll
  for (int s = 0; s < 32; s++){
    size_t idx = base + (size_t)s * 128;
    short h, l;
    split2(kg_f[idx] * __expf((float)(Lend - L[s])), h, l);   // k^ <= k
    bufh[s] = h; bufl[s] = l;
  }
  { short* dh = khTh + ((size_t)bc * 128 + kx) * 32;
    short* dl = khTl + ((size_t)bc * 128 + kx) * 32;
#pragma unroll
    for (int i = 0; i < 32; i += 8){
      *(bf16x8*)(dh + i) = *(const bf16x8*)(bufh + i);
      *(bf16x8*)(dl + i) = *(const bf16x8*)(bufl + i);
    } }
#pragma unroll
  for (int s = 0; s < 32; s++){
    short h, l;
    split2(vv_f[base + (size_t)s * 128], h, l);
    bufh[s] = h; bufl[s] = l;
  }
  { short* dh = vvTh + ((size_t)bc * 128 + kx) * 32;
    short* dl = vvTl + ((size_t)bc * 128 + kx) * 32;
#pragma unroll
    for (int i = 0; i < 32; i += 8){
      *(bf16x8*)(dh + i) = *(const bf16x8*)(bufh + i);
      *(bf16x8*)(dl + i) = *(const bf16x8*)(bufl + i);
    } }
}

// ---------------- state scan over chunks, grid = B*64 single-wave blocks ----------------
__global__ __launch_bounds__(64) void k_scan(
  const short* __restrict__ khTh, const short* __restrict__ khTl,
  const short* __restrict__ vvTh, const short* __restrict__ vvTl,
  const float* __restrict__ Dend, const float* __restrict__ cell0,
  short* __restrict__ sth, short* __restrict__ stl, float* __restrict__ Cfin)
{
  const int blk = blockIdx.x;
  const int b = blk >> 6, tile = blk & 63;
  const int kt = tile >> 3, vt = tile & 7;
  const int lane = threadIdx.x & 63;
  const int coll = lane & 15, rq = lane >> 4;
  const int kcol = kt*16 + coll;
  const int vrow0 = vt*16 + rq*4;
  const size_t cb0 = (size_t)b * 64;

  f32x4 acc;
#pragma unroll
  for (int r = 0; r < 4; r++)
    acc[r] = cell0[((size_t)b*128 + kcol)*128 + vrow0 + r];

  size_t gv = (cb0*128 + vt*16 + coll)*32 + rq*8;
  size_t gk = (cb0*128 + kt*16 + coll)*32 + rq*8;
  bf16x8 avh = *(const bf16x8*)(vvTh + gv);
  bf16x8 avl = *(const bf16x8*)(vvTl + gv);
  bf16x8 bkh = *(const bf16x8*)(khTh + gk);
  bf16x8 bkl = *(const bf16x8*)(khTl + gk);
  float d = Dend[cb0*128 + kcol];

  for (int ck = 0; ck < 64; ck++){
    const size_t cb = cb0 + ck;
    const size_t cbn = cb0 + (ck < 63 ? ck + 1 : ck);
    size_t ngv = (cbn*128 + vt*16 + coll)*32 + rq*8;
    size_t ngk = (cbn*128 + kt*16 + coll)*32 + rq*8;
    bf16x8 navh = *(const bf16x8*)(vvTh + ngv);
    bf16x8 navl = *(const bf16x8*)(vvTl + ngv);
    bf16x8 nbkh = *(const bf16x8*)(khTh + ngk);
    bf16x8 nbkl = *(const bf16x8*)(khTl + ngk);
    float nd = Dend[cbn*128 + kcol];
    {
      size_t sb = (cb*128 + vrow0)*128 + kcol;
#pragma unroll
      for (int r = 0; r < 4; r++){
        short h, l; split2(acc[r], h, l);
        sth[sb + (size_t)r*128] = h;
        stl[sb + (size_t)r*128] = l;
      }
    }
#pragma unroll
    for (int r = 0; r < 4; r++) acc[r] *= d;
    acc = MFMA(avh, bkh, acc);
    acc = MFMA(avh, bkl, acc);
    acc = MFMA(avl, bkh, acc);
    avh = navh; avl = navl; bkh = nbkh; bkl = nbkl; d = nd;
  }
  *(f32x4*)(Cfin + ((size_t)b*128 + kcol)*128 + vrow0) = acc;
}

// ---------------- per-(b,chunk) outputs (3-pass split): o^T = C^T q~^T + V^T A^T ----------------
__global__ __launch_bounds__(256) void k_chunkout(
  const short* __restrict__ qth, const short* __restrict__ qtl,
  const short* __restrict__ kth, const short* __restrict__ ktl,
  const short* __restrict__ vvTh, const short* __restrict__ vvTl,
  const short* __restrict__ sth, const short* __restrict__ stl,
  short* __restrict__ ovT, short* __restrict__ ovc,
  short* __restrict__ ovqh, short* __restrict__ ovql)
{
  __shared__ __align__(16) short ATh[32][40], ATl[32][40];
  const int bc = blockIdx.x;
  const int b = bc >> 6, ck = bc & 63;
  const int tid = threadIdx.x, lane = tid & 63, w = tid >> 6;
  const int coll = lane & 15, rq = lane >> 4;
  const size_t tbase = (size_t)b * 2048 + (size_t)ck * 32;
  {
    const int si = w >> 1, ti = w & 1;
    f32x4 aA = (f32x4){0.f,0.f,0.f,0.f};
#pragma unroll
    for (int kit = 0; kit < 4; kit++){
      size_t ga = (tbase + si*16 + coll) * 128 + kit*32 + rq*8;
      size_t gb = (tbase + ti*16 + coll) * 128 + kit*32 + rq*8;
      bf16x8 a3h = *(const bf16x8*)(kth + ga), a3l = *(const bf16x8*)(ktl + ga);
      bf16x8 b3h = *(const bf16x8*)(qth + gb), b3l = *(const bf16x8*)(qtl + gb);
      aA = MFMA(a3h, b3h, aA);
      aA = MFMA(a3h, b3l, aA);
      aA = MFMA(a3l, b3h, aA);
    }
#pragma unroll
    for (int r = 0; r < 4; r++){
      int s = si*16 + rq*4 + r, t = ti*16 + coll;
      float val = (s <= t) ? aA[r] : 0.f;     // causal mask, diag kept
      short h, l; split2(val, h, l);
      ATh[t][s] = h; ATl[t][s] = l;
    }
  }
  __syncthreads();
  const int vb = w * 32;
  f32x4 o[2][2];
#pragma unroll
  for (int vi = 0; vi < 2; vi++)
#pragma unroll
    for (int ti = 0; ti < 2; ti++) o[vi][ti] = (f32x4){0.f,0.f,0.f,0.f};
#pragma unroll
  for (int kit = 0; kit < 4; kit++){
    bf16x8 aCh[2], aCl[2], bqh[2], bql[2];
#pragma unroll
    for (int vi = 0; vi < 2; vi++){
      size_t g = ((size_t)bc * 128 + vb + vi*16 + coll) * 128 + kit*32 + rq*8;
      aCh[vi] = *(const bf16x8*)(sth + g);
      aCl[vi] = *(const bf16x8*)(stl + g);
    }
#pragma unroll
    for (int ti = 0; ti < 2; ti++){
      size_t g = (tbase + ti*16 + coll) * 128 + kit*32 + rq*8;
      bqh[ti] = *(const bf16x8*)(qth + g);
      bql[ti] = *(const bf16x8*)(qtl + g);
    }
#pragma unroll
    for (int vi = 0; vi < 2; vi++)
#pragma unroll
      for (int ti = 0; ti < 2; ti++){
        o[vi][ti] = MFMA(aCh[vi], bqh[ti], o[vi][ti]);
        o[vi][ti] = MFMA(aCh[vi], bql[ti], o[vi][ti]);
        o[vi][ti] = MFMA(aCl[vi], bqh[ti], o[vi][ti]);
      }
  }
  {
    bf16x8 a2h[2], a2l[2], b2h[2], b2l[2];
#pragma unroll
    for (int vi = 0; vi < 2; vi++){
      size_t g = ((size_t)bc * 128 + vb + vi*16 + coll) * 32 + rq*8;
      a2h[vi] = *(const bf16x8*)(vvTh + g);
      a2l[vi] = *(const bf16x8*)(vvTl + g);
    }
#pragma unroll
    for (int ti = 0; ti < 2; ti++){
      b2h[ti] = *(const bf16x8*)&ATh[ti*16 + coll][rq*8];
      b2l[ti] = *(const bf16x8*)&ATl[ti*16 + coll][rq*8];
    }
#pragma unroll
    for (int vi = 0; vi < 2; vi++)
#pragma unroll
      for (int ti = 0; ti < 2; ti++){
        o[vi][ti] = MFMA(a2h[vi], b2h[ti], o[vi][ti]);
        o[vi][ti] = MFMA(a2h[vi], b2l[ti], o[vi][ti]);
        o[vi][ti] = MFMA(a2l[vi], b2h[ti], o[vi][ti]);
      }
  }
#pragma unroll
  for (int vi = 0; vi < 2; vi++)
#pragma unroll
  for (int ti = 0; ti < 2; ti++)
#pragma unroll
  for (int r = 0; r < 4; r++){
    int v = vb + vi*16 + rq*4 + r;
    int tl = ti*16 + coll;
    float val = o[vi][ti][r];
    short h, l; split2(val, h, l);
    ovT[((size_t)b * 128 + v) * 2048 + (size_t)ck * 32 + tl] = h;  // [b][v][t] bf16 (PV operand)
    ovc[(tbase + tl) * 256 + v] = h;                                // [b][t][0:128] bf16
    ovqh[(tbase + tl) * 128 + v] = h;                               // split ov for scores
    ovql[(tbase + tl) * 128 + v] = l;
  }
}

// ---------------- causal softmax attention: flash-decoding split-S (P=8 x 256) ----------------
__global__ __launch_bounds__(256) void k_attn(
  const short* __restrict__ ovqh, const short* __restrict__ ovql,
  const short* __restrict__ ovT,
  float* __restrict__ m_part, float* __restrict__ l_part,
  short* __restrict__ oa_part)
{
  const int qi = blockIdx.x, b = blockIdx.y, p = blockIdx.z;
  const int qbase = qi * 64;
  const int ps = p * 256;
  const size_t obase = (size_t)b * 2048;
  const int tid = threadIdx.x;
  if (ps > qbase + 63){
    if (tid < 64) l_part[((obase + qbase + tid) << 3) + p] = 0.f;
    return;
  }
  __shared__ __align__(16) short P[4][16][40];
  const int lane = tid & 63, w = tid >> 6;
  const int coll = lane & 15, rq = lane >> 4;
  const int tw = qbase + w * 16;
  bf16x8 qfh[4], qfl[4];
#pragma unroll
  for (int kit = 0; kit < 4; kit++){
    size_t g = (obase + tw + coll) * 128 + kit*32 + rq*8;
    qfh[kit] = *(const bf16x8*)(ovqh + g);
    qfl[kit] = *(const bf16x8*)(ovql + g);
  }
  float m[4], l[4];
  f32x4 oa[8];
#pragma unroll
  for (int r = 0; r < 4; r++){ m[r] = -1e30f; l[r] = 0.f; }
#pragma unroll
  for (int df = 0; df < 8; df++) oa[df] = (f32x4){0.f,0.f,0.f,0.f};
  const int send = min(tw + 15, ps + 255);
  for (int s0 = ps; s0 <= send; s0 += 32){
    f32x4 sc[2];
#pragma unroll
    for (int sf = 0; sf < 2; sf++){
      bf16x8 kh[4], kl[4];
#pragma unroll
      for (int kit = 0; kit < 4; kit++){
        size_t g = (obase + s0 + sf*16 + coll) * 128 + kit*32 + rq*8;
        kh[kit] = *(const bf16x8*)(ovqh + g);
        kl[kit] = *(const bf16x8*)(ovql + g);
      }
      f32x4 c0 = (f32x4){0.f,0.f,0.f,0.f};
      f32x4 c1 = (f32x4){0.f,0.f,0.f,0.f};
      f32x4 c2 = (f32x4){0.f,0.f,0.f,0.f};
#pragma unroll
      for (int kit = 0; kit < 4; kit++){
        c0 = MFMA(qfh[kit], kh[kit], c0);
        c1 = MFMA(qfh[kit], kl[kit], c1);
        c2 = MFMA(qfl[kit], kh[kit], c2);
      }
      sc[sf] = c0 + c1 + c2;
    }
    bf16x8 vf[8];
#pragma unroll
    for (int df = 0; df < 8; df++)
      vf[df] = *(const bf16x8*)(ovT + ((size_t)b*128 + df*16 + coll)*2048 + s0 + rq*8);
#pragma unroll
    for (int r = 0; r < 4; r++){
      int trow = tw + rq*4 + r;
      float s0v = (s0 + coll      <= trow) ? sc[0][r] : -1e30f;
      float s1v = (s0 + 16 + coll <= trow) ? sc[1][r] : -1e30f;
      float mx = fmaxf(s0v, s1v);
#pragma unroll
      for (int d = 1; d < 16; d <<= 1) mx = fmaxf(mx, __shfl_xor(mx, d));
      float mn = fmaxf(m[r], mx);
      float scale = __expf(m[r] - mn);
      float p0 = __expf(s0v - mn);
      float p1 = __expf(s1v - mn);
      float rs = p0 + p1;
#pragma unroll
      for (int d = 1; d < 16; d <<= 1) rs += __shfl_xor(rs, d);
      l[r] = l[r] * scale + rs;
      m[r] = mn;
#pragma unroll
      for (int df = 0; df < 8; df++) oa[df][r] *= scale;
      P[w][rq*4 + r][coll]      = f2b(p0);
      P[w][rq*4 + r][16 + coll] = f2b(p1);
    }
    bf16x8 pf = *(const bf16x8*)&P[w][coll][rq*8];
#pragma unroll
    for (int df = 0; df < 8; df++)
      oa[df] = MFMA(pf, vf[df], oa[df]);
  }
#pragma unroll
  for (int r = 0; r < 4; r++){
    int t = tw + rq*4 + r;
    size_t idx8 = ((obase + t) << 3) + p;
    if (coll == 0){ m_part[idx8] = m[r]; l_part[idx8] = l[r]; }
#pragma unroll
    for (int df = 0; df < 8; df++)
      oa_part[idx8*128 + df*16 + coll] = f2b(oa[df][r]);
  }
}

// ---------------- LSE combine of 8 partials -> ctx (ovc[...,128:256]) ----------------
__global__ __launch_bounds__(256) void k_comb(
  const float* __restrict__ m_part, const float* __restrict__ l_part,
  const short* __restrict__ oa_part, short* __restrict__ ovc)
{
  const int blk = blockIdx.x;          // b*32 + qi
  const int b = blk >> 5, qi = blk & 31;
  const int row = threadIdx.x >> 2, cg = threadIdx.x & 3;
  const int t = qi*64 + row;
  const size_t base8 = ((size_t)b*2048 + t) * 8;
  float mv[8], lv[8];
#pragma unroll
  for (int p = 0; p < 8; p++){ mv[p] = m_part[base8+p]; lv[p] = l_part[base8+p]; }
  float M = -3e38f;
#pragma unroll
  for (int p = 0; p < 8; p++) if (lv[p] > 0.f) M = fmaxf(M, mv[p]);
  float L = 0.f, wgt[8];
#pragma unroll
  for (int p = 0; p < 8; p++){
    wgt[p] = (lv[p] > 0.f) ? __expf(mv[p] - M) : 0.f;
    L += lv[p] * wgt[p];
  }
  const float inv = 1.f / L;
  const int v0 = cg * 32;
  float acc[32];
#pragma unroll
  for (int j = 0; j < 32; j++) acc[j] = 0.f;
#pragma unroll
  for (int p = 0; p < 8; p++){
    if (lv[p] > 0.f){
      const short* src = oa_part + (base8 + p)*128 + v0;
#pragma unroll
      for (int jo = 0; jo < 32; jo += 8){
        bf16x8 x = *(const bf16x8*)(src + jo);
#pragma unroll
        for (int j = 0; j < 8; j++) acc[jo+j] += b2f(x[j]) * wgt[p];
      }
    }
  }
  short* dst = ovc + ((size_t)b*2048 + t)*256 + 128 + v0;
#pragma unroll
  for (int jo = 0; jo < 32; jo += 8){
    bf16x8 o;
#pragma unroll
    for (int j = 0; j < 8; j++) o[j] = f2b(acc[jo+j] * inv);
    *(bf16x8*)(dst + jo) = o;
  }
}

// ---------------- output GEMM (bf16 NT, m97-style): out = concat(ov,ctx) @ OW^T + b ----------
// BM=128, BN=64, BK=64, KD=256 -> 4 steps. grid (64, 8).
__global__ __launch_bounds__(256) void k_gemm0(
  const short* __restrict__ A, const short* __restrict__ Bw,
  const float* __restrict__ bias, float* __restrict__ out)
{
  __shared__ __align__(16) short At[128*64];
  __shared__ __align__(16) short Bt[64*64];
  const int m0 = blockIdx.x * 128;
  const int ny = blockIdx.y;
  const int tid = threadIdx.x, lane = tid & 63, w = tid >> 6;
  const int wr = w >> 1, wc = w & 1;
  const int coll = lane & 15, rq = lane >> 4;
  f32x4 acc[4][2];
#pragma unroll
  for (int i = 0; i < 4; i++)
#pragma unroll
    for (int j = 0; j < 2; j++) acc[i][j] = (f32x4){0.f,0.f,0.f,0.f};

  for (int step = 0; step < 4; ++step){
    const int k0 = step * 64;
    __syncthreads();
#pragma unroll
    for (int t = 0; t < 4; ++t){
      int ci = t*256 + tid;
      int row = ci >> 3;
      int cs = (ci & 7) ^ (row & 7);
      gload16(A + (size_t)(m0 + row)*256 + k0 + cs*8, At + ci*8);
    }
#pragma unroll
    for (int t = 0; t < 2; ++t){
      int ci = t*256 + tid;
      int row = ci >> 3;
      int cs = (ci & 7) ^ (row & 7);
      gload16(Bw + (size_t)(ny*64 + row)*256 + k0 + cs*8, Bt + ci*8);
    }
    __syncthreads();
#pragma unroll
    for (int kk = 0; kk < 2; ++kk){
      bf16x8 a[4], b[2];
#pragma unroll
      for (int mi = 0; mi < 4; mi++){
        int ar = wr*64 + mi*16 + coll;
        a[mi] = *(const bf16x8*)&At[ar*64 + (((kk*4+rq) ^ (ar & 7))*8)];
      }
#pragma unroll
      for (int ni = 0; ni < 2; ni++){
        int br = wc*32 + ni*16 + coll;
        b[ni] = *(const bf16x8*)&Bt[br*64 + (((kk*4+rq) ^ (br & 7))*8)];
      }
#pragma unroll
      for (int mi = 0; mi < 4; mi++)
#pragma unroll
        for (int ni = 0; ni < 2; ni++)
          acc[mi][ni] = MFMA(a[mi], b[ni], acc[mi][ni]);
    }
  }
#pragma unroll
  for (int mi = 0; mi < 4; mi++)
#pragma unroll
  for (int ni = 0; ni < 2; ni++){
    int gn = ny*64 + wc*32 + ni*16 + coll;
    float bsv = bias[gn];
#pragma unroll
    for (int r = 0; r < 4; r++){
      int gm = m0 + wr*64 + mi*16 + rq*4 + r;
      out[(size_t)gm * 512 + gn] = acc[mi][ni][r] + bsv;
    }
  }
}

// ---------------- host launch ----------------
extern "C" void kernel_launch(void* const* d_in, const int* in_sizes, int n_in,
                              void* d_out, int out_size, void* d_ws, size_t ws_size,
                              hipStream_t stream){
  const float* hidden = (const float*)d_in[0];   // (4,2048,512)
  const float* cell0  = (const float*)d_in[1];   // (4,128,128)
  const float* projw  = (const float*)d_in[2];   // (512,512)
  const float* projb  = (const float*)d_in[3];   // (512,)
  const float* outw   = (const float*)d_in[4];   // (512,256)
  const float* outb   = (const float*)d_in[5];   // (512,)
  float* out = (float*)d_out;

  char* ws = (char*)d_ws;
  size_t off = 0;
  auto alloc = [&](size_t bytes) -> void* {
    void* p = ws + off;
    off += (bytes + 255) & ~(size_t)255;
    return p;
  };
  // Arena A: X split (phase 1) -> ov buffers (phase 2). 16.78 MB.
  short* Xh   = (short*)alloc(8192ULL * 512 * 2);
  short* Xl   = (short*)alloc(8192ULL * 512 * 2);
  short* ovqh = Xh;                       // 8192*128 shorts
  short* ovql = Xh + 1048576;
  short* ovT  = Xh + 2097152;             // 4*128*2048 shorts
  short* ovc  = Xh + 3145728;             // 8192*256 shorts
  // Arena B: q/kg/lg/vv f32 (phase 1) -> states hi/lo -> oa partials (attn). 16.78 MB.
  float* q_f  = (float*)alloc(8192ULL * 128 * 4);
  float* kg_f = (float*)alloc(8192ULL * 128 * 4);
  float* lg_f = (float*)alloc(8192ULL * 128 * 4);
  float* vv_f = (float*)alloc(8192ULL * 128 * 4);
  short* sth  = (short*)q_f;              // 256*128*128 shorts
  short* stl  = sth + 4194304;
  short* oa_part = (short*)q_f;           // 4*2048*8*128 shorts
  // Persistent
  short* Wh   = (short*)alloc(512ULL * 512 * 2);
  short* Wl   = (short*)alloc(512ULL * 512 * 2);
  short* OWbf = (short*)alloc(512ULL * 256 * 2);
  short* qth  = (short*)alloc(8192ULL * 128 * 2);
  short* qtl  = (short*)alloc(8192ULL * 128 * 2);
  short* kth  = (short*)alloc(8192ULL * 128 * 2);
  short* ktl  = (short*)alloc(8192ULL * 128 * 2);
  short* khTh = (short*)alloc(256ULL * 128 * 32 * 2);
  short* khTl = (short*)alloc(256ULL * 128 * 32 * 2);
  short* vvTh = (short*)alloc(256ULL * 128 * 32 * 2);
  short* vvTl = (short*)alloc(256ULL * 128 * 32 * 2);
  float* Dend = (float*)alloc(256ULL * 128 * 4);
  float* m_part = (float*)alloc(4ULL * 2048 * 8 * 4);
  float* l_part = (float*)alloc(4ULL * 2048 * 8 * 4);

  k_split<<<4096, 256, 0, stream>>>(hidden, Xh, Xl, 8192 * 512);
  k_split<<<256,  256, 0, stream>>>(projw,  Wh, Wl, 512 * 512);
  k_cvt<<<128, 256, 0, stream>>>(outw, OWbf, 512 * 256);

  k_gemm1<<<dim3(64, 8), 256, 0, stream>>>(Xh, Xl, Wh, Wl, projb, q_f, kg_f, lg_f, vv_f);
  k_prep<<<256, 128, 0, stream>>>(q_f, kg_f, lg_f, vv_f,
                                  qth, qtl, kth, ktl, khTh, khTl, vvTh, vvTl, Dend);
  k_scan<<<256, 64, 0, stream>>>(khTh, khTl, vvTh, vvTl, Dend, cell0,
                                 sth, stl, out + 8192ULL * 512);
  k_chunkout<<<256, 256, 0, stream>>>(qth, qtl, kth, ktl, vvTh, vvTl, sth, stl,
                                      ovT, ovc, ovqh, ovql);
  k_attn<<<dim3(32, 4, 8), 256, 0, stream>>>(ovqh, ovql, ovT, m_part, l_part, oa_part);
  k_comb<<<128, 256, 0, stream>>>(m_part, l_part, oa_part, ovc);
  k_gemm0<<<dim3(64, 8), 256, 0, stream>>>(ovc, OWbf, outb, out);
}